// Round 9
// baseline (195.612 us; speedup 1.0000x reference)
//
#include <hip/hip_runtime.h>
#include <hip/hip_bf16.h>

typedef __hip_bfloat16 bf16;
typedef __attribute__((ext_vector_type(8))) short short8;
typedef __attribute__((ext_vector_type(4))) float f32x4;

#define B_  4
#define T_  1024
#define D_  512
#define H_  8
#define DK_ 64
#define L_  2047   // 2*T - 1

__device__ __forceinline__ float b2f(bf16 v) { return __bfloat162float(v); }
__device__ __forceinline__ bf16  f2b(float v) { return __float2bfloat16(v); }
__device__ __forceinline__ float bits2f(unsigned short u) {
    return __uint_as_float(((unsigned int)u) << 16);
}
__device__ __forceinline__ unsigned short fbits(float v) {
    bf16 h = f2b(v); return *(unsigned short*)&h;
}

#define MFMA16(a, b, c) __builtin_amdgcn_mfma_f32_16x16x32_bf16(a, b, c, 0, 0, 0)
#define GLD_LDS16(g, l) __builtin_amdgcn_global_load_lds( \
    (const __attribute__((address_space(1))) unsigned int*)(g), \
    (__attribute__((address_space(3))) unsigned int*)(l), 16, 0, 0)

// ============ prep_all: weight transpose + bias concat + pos cvt + layernorm ============
// flat grid: [0,1280) weights, [1280,1286) bias, [1286,3333) pos_cvt, [3333,7429) lnorm
__global__ __launch_bounds__(256) void prep_all(
        const float* __restrict__ Wq, const float* __restrict__ Wk,
        const float* __restrict__ Wv, const float* __restrict__ Wp,
        const float* __restrict__ Wo,
        const float* __restrict__ bq, const float* __restrict__ bk,
        const float* __restrict__ bv,
        const float* __restrict__ pos, const float* __restrict__ x,
        const float* __restrict__ gamma, const float* __restrict__ beta,
        bf16* __restrict__ Wqkv_t, bf16* __restrict__ Wp_t, bf16* __restrict__ Wo_t,
        float* __restrict__ biasq, bf16* __restrict__ pos_bf, bf16* __restrict__ y) {
    __shared__ float tl[32][33];
    __shared__ float ws1[4], ws2[4];
    const int blk = blockIdx.x;
    const int t = threadIdx.x;

    if (blk < 1280) {            // ---- weight transpose: f32 [k][n] -> bf16 [n][k] ----
        const int z = blk >> 8, rem = blk & 255;
        const float* W; bf16* Wt; int roff;
        switch (z) {
            case 0: W = Wq; Wt = Wqkv_t; roff = 0;    break;
            case 1: W = Wk; Wt = Wqkv_t; roff = 512;  break;
            case 2: W = Wv; Wt = Wqkv_t; roff = 1024; break;
            case 3: W = Wp; Wt = Wp_t;   roff = 0;    break;
            default: W = Wo; Wt = Wo_t;  roff = 0;    break;
        }
        const int n0 = (rem & 15) * 32, k0 = (rem >> 4) * 32;
        const int tx = t & 31, ty = t >> 5;
#pragma unroll
        for (int r = 0; r < 4; ++r)
            tl[ty + r * 8][tx] = W[(size_t)(k0 + ty + r * 8) * 512 + n0 + tx];
        __syncthreads();
#pragma unroll
        for (int r = 0; r < 4; ++r)
            Wt[(size_t)(roff + n0 + ty + r * 8) * 512 + k0 + tx] = f2b(tl[tx][ty + r * 8]);
    } else if (blk < 1286) {     // ---- bias concat ----
        int i = (blk - 1280) * 256 + t;
        biasq[i] = (i < 512) ? bq[i] : (i < 1024) ? bk[i - 512] : bv[i - 1024];
    } else if (blk < 3333) {     // ---- pos f32 -> bf16 ----
        size_t i = ((size_t)(blk - 1286) * 256 + t) * 8;
        float4 a = *(const float4*)(pos + i);
        float4 c = *(const float4*)(pos + i + 4);
        uint4 wv;
        wv.x = ((unsigned)fbits(a.y) << 16) | fbits(a.x);
        wv.y = ((unsigned)fbits(a.w) << 16) | fbits(a.z);
        wv.z = ((unsigned)fbits(c.y) << 16) | fbits(c.x);
        wv.w = ((unsigned)fbits(c.w) << 16) | fbits(c.z);
        *(uint4*)((unsigned short*)pos_bf + i) = wv;
    } else {                     // ---- layernorm row ----
        const int row = blk - 3333;
        const float* xr = x + (size_t)row * D_;
        float v0 = xr[t];
        float v1 = xr[t + 256];
        float s  = v0 + v1;
        float s2 = v0 * v0 + v1 * v1;
#pragma unroll
        for (int off = 32; off > 0; off >>= 1) {
            s  += __shfl_down(s,  off, 64);
            s2 += __shfl_down(s2, off, 64);
        }
        const int wid = t >> 6, lane = t & 63;
        if (!lane) { ws1[wid] = s; ws2[wid] = s2; }
        __syncthreads();
        float S  = ws1[0] + ws1[1] + ws1[2] + ws1[3];
        float S2 = ws2[0] + ws2[1] + ws2[2] + ws2[3];
        float mean = S * (1.f / D_);
        float var  = S2 * (1.f / D_) - mean * mean;
        float r = rsqrtf(var + 1e-3f);
        bf16* yr = y + (size_t)row * D_;
        yr[t]       = f2b((v0 - mean) * r * gamma[t]       + beta[t]);
        yr[t + 256] = f2b((v1 - mean) * r * gamma[t + 256] + beta[t + 256]);
    }
}

// ============ MFMA GEMM body: [M,512] x Wt^T (Wt: [N][512] bf16), 128x128 ============
// BK=64 (two stacked 32-col half-tiles -> identical conflict-free reads and
// wave-linear gl_lds dests as BK=32) -> 8 barrier-drains instead of 16.
__device__ __forceinline__ void gemm_body(
        const bf16* __restrict__ A, const bf16* __restrict__ Wt,
        const float* __restrict__ bias,
        bf16* __restrict__ C, int M, size_t seg_elems, int m0, int n0,
        unsigned short (*A_s)[32], unsigned short (*B_s)[32]) {   // [512][32] = 2 bufs
    const int t = threadIdx.x;
    const int w = t >> 6, lane = t & 63;
    const int quad = lane >> 4, n16 = lane & 15;
    const int wm = (w >> 1) * 64, wn = (w & 1) * 64;

    f32x4 acc[4][4];
#pragma unroll
    for (int a = 0; a < 4; ++a)
#pragma unroll
        for (int b = 0; b < 4; ++b) acc[a][b] = (f32x4){0.f, 0.f, 0.f, 0.f};

    const int ar = lane >> 2, ac8 = (lane & 3) * 8;
    auto stage = [&](int k0, int buf) {   // stage 64 K-cols as 2 half-tiles
        const int bo = buf << 8;          // 256 rows per buffer
#pragma unroll
        for (int kc = 0; kc < 2; ++kc)
#pragma unroll
            for (int ps = 0; ps < 2; ++ps) {
                int br = (ps * 4 + w) * 16;
                GLD_LDS16(A  + (size_t)(m0 + br + ar) * 512 + k0 + kc * 32 + ac8,
                          &A_s[bo + kc * 128 + br][0]);
                GLD_LDS16(Wt + (size_t)(n0 + br + ar) * 512 + k0 + kc * 32 + ac8,
                          &B_s[bo + kc * 128 + br][0]);
            }
    };
    stage(0, 0);
    int cur = 0;
    for (int k0 = 0; k0 < 512; k0 += 64) {
        __syncthreads();                    // drains cur loads; cur^1 reads done
        if (k0 + 64 < 512) stage(k0 + 64, cur ^ 1);
        const int bo = cur << 8;
#pragma unroll
        for (int kc = 0; kc < 2; ++kc) {
            short8 af[4], bfr[4];
#pragma unroll
            for (int i = 0; i < 4; ++i) {
                af[i]  = *(const short8*)&A_s[bo + kc * 128 + wm + i * 16 + n16][quad * 8];
                bfr[i] = *(const short8*)&B_s[bo + kc * 128 + wn + i * 16 + n16][quad * 8];
            }
#pragma unroll
            for (int mi = 0; mi < 4; ++mi)
#pragma unroll
                for (int ni = 0; ni < 4; ++ni)
                    acc[mi][ni] = MFMA16(af[mi], bfr[ni], acc[mi][ni]);
        }
        cur ^= 1;
    }

    const int seg = n0 >> 9;
#pragma unroll
    for (int mi = 0; mi < 4; ++mi) {
#pragma unroll
        for (int r = 0; r < 4; ++r) {
            int row = m0 + wm + mi * 16 + quad * 4 + r;
            if (row >= M) continue;
#pragma unroll
            for (int ni = 0; ni < 4; ++ni) {
                int col  = n0 + wn + ni * 16 + n16;
                int coll = col & 511;
                float vv = acc[mi][ni][r];
                if (bias) vv += bias[col];
                bf16* Cp = C + seg * seg_elems;
                Cp[(size_t)row * 512 + coll] = f2b(vv);
            }
        }
    }
}

// qkv GEMM (384 blocks, 128x128) + p GEMM (512 blocks, 64x128) in one launch.
// XCD-aware decode (xcd = gid&7) keeps A-panel reuse within one XCD's L2.
__global__ __launch_bounds__(256) void gemm_qkvp(
        const bf16* __restrict__ y, const bf16* __restrict__ pos_bf,
        const bf16* __restrict__ Wqkv_t, const bf16* __restrict__ Wp_t,
        const float* __restrict__ biasq,
        bf16* __restrict__ q, bf16* __restrict__ p, size_t seg_elems) {
    __shared__ __align__(16) unsigned short A_s[512][32];
    __shared__ __align__(16) unsigned short B_s[512][32];
    const int gid = blockIdx.x;
    if (gid < 384) {
        const int xcd = gid & 7, s = gid >> 3;       // s: 0..47
        const int n = s % 12;
        const int m = xcd * 4 + s / 12;              // 0..31
        gemm_body(y, Wqkv_t, biasq, q, 4096, seg_elems, m * 128, n * 128, A_s, B_s);
    } else {
        // ---- p: [8188,512] x [512,512], 64x128 tiles, BK=64 ----
        const int g2 = gid - 384;                    // 0..511 (384%8==0)
        const int xcd = g2 & 7, s = g2 >> 3;         // s: 0..63
        const int n0 = (s & 3) * 128;
        const int m0 = (xcd * 16 + (s >> 2)) * 64;   // 128 m-tiles of 64 rows
        const int t = threadIdx.x;
        const int w = t >> 6, lane = t & 63;
        const int quad = lane >> 4, n16 = lane & 15;
        const int wm = (w >> 1) * 32, wn = (w & 1) * 64;

        f32x4 acc[2][4];
#pragma unroll
        for (int a = 0; a < 2; ++a)
#pragma unroll
            for (int b = 0; b < 4; ++b) acc[a][b] = (f32x4){0.f, 0.f, 0.f, 0.f};

        const int ar = lane >> 2, ac8 = (lane & 3) * 8;
        // A loads for rows up to 8191 stay inside pos_bf's 8 MB d_out region
        // (8192*1024B == d_out size); stores are M-guarded.
        auto stage = [&](int k0, int buf) {
            const int boA = buf * 128, boB = buf * 256;
#pragma unroll
            for (int kc = 0; kc < 2; ++kc) {
                GLD_LDS16(pos_bf + (size_t)(m0 + w * 16 + ar) * 512 + k0 + kc * 32 + ac8,
                          &A_s[boA + kc * 64 + w * 16][0]);
#pragma unroll
                for (int ps = 0; ps < 2; ++ps)
                    GLD_LDS16(Wp_t + (size_t)(n0 + (ps * 4 + w) * 16 + ar) * 512 + k0 + kc * 32 + ac8,
                              &B_s[boB + kc * 128 + (ps * 4 + w) * 16][0]);
            }
        };
        stage(0, 0);
        int cur = 0;
        for (int k0 = 0; k0 < 512; k0 += 64) {
            __syncthreads();
            if (k0 + 64 < 512) stage(k0 + 64, cur ^ 1);
            const int boA = cur * 128, boB = cur * 256;
#pragma unroll
            for (int kc = 0; kc < 2; ++kc) {
                short8 af[2], bfr[4];
#pragma unroll
                for (int i = 0; i < 2; ++i)
                    af[i] = *(const short8*)&A_s[boA + kc * 64 + wm + i * 16 + n16][quad * 8];
#pragma unroll
                for (int i = 0; i < 4; ++i)
                    bfr[i] = *(const short8*)&B_s[boB + kc * 128 + wn + i * 16 + n16][quad * 8];
#pragma unroll
                for (int mi = 0; mi < 2; ++mi)
#pragma unroll
                    for (int ni = 0; ni < 4; ++ni)
                        acc[mi][ni] = MFMA16(af[mi], bfr[ni], acc[mi][ni]);
            }
            cur ^= 1;
        }
#pragma unroll
        for (int mi = 0; mi < 2; ++mi) {
#pragma unroll
            for (int r = 0; r < 4; ++r) {
                int row = m0 + wm + mi * 16 + quad * 4 + r;
                if (row >= 8188) continue;
#pragma unroll
                for (int ni = 0; ni < 4; ++ni) {
                    int col = n0 + wn + ni * 16 + n16;
                    p[(size_t)row * 512 + col] = f2b(acc[mi][ni][r]);
                }
            }
        }
    }
}

// out-projection: 64x64 tiles -> 512 blocks (2/CU, full machine), BK=64
// (8 barrier-drains).  acc + bias + residual fused, f32 store.  XCD m-grouping.
__global__ __launch_bounds__(256) void gemm_out(
        const bf16* __restrict__ o, const bf16* __restrict__ Wo_t,
        const float* __restrict__ bo, const float* __restrict__ x,
        float* __restrict__ out) {
    __shared__ __align__(16) unsigned short A_s[256][32];   // 2 bufs x 2 kc x 64 rows
    __shared__ __align__(16) unsigned short B_s[256][32];
    const int gid = blockIdx.x;                     // 0..511
    const int xcd = gid & 7, s = gid >> 3;          // s: 0..63
    const int n0 = (s & 7) * 64;
    const int m0 = (xcd * 8 + (s >> 3)) * 64;       // 64 m-tiles of 64 rows
    const int t = threadIdx.x;
    const int w = t >> 6, lane = t & 63;
    const int quad = lane >> 4, n16 = lane & 15;
    const int wm = (w >> 1) * 32, wn = (w & 1) * 32;

    f32x4 acc[2][2];
#pragma unroll
    for (int a = 0; a < 2; ++a)
#pragma unroll
        for (int b = 0; b < 2; ++b) acc[a][b] = (f32x4){0.f, 0.f, 0.f, 0.f};

    const int ar = lane >> 2, ac8 = (lane & 3) * 8;
    auto stage = [&](int k0, int buf) {
        const int bo = buf * 128;
#pragma unroll
        for (int kc = 0; kc < 2; ++kc) {
            GLD_LDS16(o    + (size_t)(m0 + w * 16 + ar) * 512 + k0 + kc * 32 + ac8,
                      &A_s[bo + kc * 64 + w * 16][0]);
            GLD_LDS16(Wo_t + (size_t)(n0 + w * 16 + ar) * 512 + k0 + kc * 32 + ac8,
                      &B_s[bo + kc * 64 + w * 16][0]);
        }
    };
    stage(0, 0);
    int cur = 0;
    for (int k0 = 0; k0 < 512; k0 += 64) {
        __syncthreads();
        if (k0 + 64 < 512) stage(k0 + 64, cur ^ 1);
        const int bo = cur * 128;
#pragma unroll
        for (int kc = 0; kc < 2; ++kc) {
            short8 af[2], bfr[2];
#pragma unroll
            for (int i = 0; i < 2; ++i) {
                af[i]  = *(const short8*)&A_s[bo + kc * 64 + wm + i * 16 + n16][quad * 8];
                bfr[i] = *(const short8*)&B_s[bo + kc * 64 + wn + i * 16 + n16][quad * 8];
            }
#pragma unroll
            for (int mi = 0; mi < 2; ++mi)
#pragma unroll
                for (int ni = 0; ni < 2; ++ni)
                    acc[mi][ni] = MFMA16(af[mi], bfr[ni], acc[mi][ni]);
        }
        cur ^= 1;
    }
#pragma unroll
    for (int mi = 0; mi < 2; ++mi) {
#pragma unroll
        for (int r = 0; r < 4; ++r) {
            int row = m0 + wm + mi * 16 + quad * 4 + r;
#pragma unroll
            for (int ni = 0; ni < 2; ++ni) {
                int col = n0 + wn + ni * 16 + n16;
                out[(size_t)row * 512 + col] =
                    acc[mi][ni][r] + bo[col] + x[(size_t)row * 512 + col];
            }
        }
    }
}

// ============ Fused MFMA flash attention, v9: P direct-from-global ==========
// v8 pipeline + O^T epilogue, with pw_s ELIMINATED: each wave's 10 P
// B-fragments per tile are wave-specific (pwoff depends on w), so they are
// loaded straight from global (L2-resident, ~262KB per (b,h)) into registers,
// prefetched one tile ahead.  Byte-identical fragment values -> bitwise-same
// output.  Effects: barrier drains 2 gl_lds instead of 6; pw LDS round-trip
// gone (fewer bank conflicts); LDS 77.8 -> 44.5 KB.
__global__ __launch_bounds__(256, 2) void attn_mfma_kernel(
        const bf16* __restrict__ q, const bf16* __restrict__ k,
        const bf16* __restrict__ v, const bf16* __restrict__ p,
        const float* __restrict__ cbias, const float* __restrict__ pbias,
        bf16* __restrict__ o) {
    __shared__ __align__(16) unsigned short k_s[2][4096];     // 64 rows x 64
    __shared__ __align__(16) unsigned short vt_s[2][64][72];  // V^T [d][j], padded
    __shared__ __align__(16) unsigned short gbuf[4][16][72];  // P tile per wave
    __shared__ float cb_s[64], pb_s[64];
    __shared__ float wrap_s;

    const int i0 = blockIdx.x * 64;
    const int h  = blockIdx.y;
    const int b  = blockIdx.z;
    const int t  = threadIdx.x;
    const int w    = t >> 6;
    const int lane = t & 63;
    const int quad = lane >> 4;
    const int n16  = lane & 15;
    const int h64  = h * 64;
    const float sc_scale = 0.125f * 1.4426950408889634f;   // (1/8)*log2(e)

    if (t < 64)       cb_s[t]      = cbias[h64 + t];
    else if (t < 128) pb_s[t - 64] = pbias[h64 + t - 64];

    // ---- K staging sources (inverse-swizzled global addresses) ----
    const int l8 = lane >> 3, l7 = lane & 7;
    const int clog8 = (l7 ^ l8) * 8;          // logical chunk for this lane's LDS slot
    const unsigned short* ksrc[2];
#pragma unroll
    for (int ps = 0; ps < 2; ++ps) {
        int row = (w * 2 + ps) * 8 + l8;
        ksrc[ps] = (const unsigned short*)k + ((size_t)(b * T_ + row) * 512 + h64 + clog8);
    }
    auto stage = [&](int j0n, int nxt) {
        size_t joff = (size_t)j0n * 512;
#pragma unroll
        for (int ps = 0; ps < 2; ++ps)
            GLD_LDS16(ksrc[ps] + joff, &k_s[nxt][(w * 2 + ps) * 512]);
    };

    // ---- P: direct global->register fragments, prefetched one tile ahead ----
    // Fragment (ct,kc) of tile j0: row = slb + pwoff + n16 + j0 + ct*16,
    // cols h64 + kc*32 + quad*8 .. +7 (16B aligned).  Same bytes the old
    // pw_s staging delivered.  Max row (i0=0, j0=960) stays inside workspace.
    const int slb   = T_ - i0 - 63;           // >= 1
    const int pwoff = 48 - 16 * w;
    const unsigned short* pbase = (const unsigned short*)p +
        ((size_t)(b * L_ + slb + pwoff + n16) * 512 + h64 + quad * 8);
    uint4 pReg[10];
    auto pload = [&](int j0n) {
#pragma unroll
        for (int kc = 0; kc < 2; ++kc)
#pragma unroll
            for (int ct = 0; ct < 5; ++ct)
                pReg[kc * 5 + ct] =
                    *(const uint4*)(pbase + (size_t)(j0n + ct * 16) * 512 + kc * 32);
    };

    // ---- V: reg-staged transpose (needs scatter, so no global_load_lds) ----
    const int vd2 = (t & 31) * 2, vjg = t >> 5;
    const unsigned short* vsrc = (const unsigned short*)v +
        ((size_t)(b * T_ + vjg * 8) * 512 + h64 + vd2);
    unsigned int vReg[8];
    auto vload = [&](int j0n) {
        const unsigned short* vg = vsrc + (size_t)j0n * 512;
#pragma unroll
        for (int e = 0; e < 8; ++e) vReg[e] = *(const unsigned int*)(vg + (size_t)e * 512);
    };
    auto vwrite = [&](int nxt) {
        uint4 wlo, whi;
        wlo.x = (vReg[0] & 0xffffu) | (vReg[1] << 16);
        wlo.y = (vReg[2] & 0xffffu) | (vReg[3] << 16);
        wlo.z = (vReg[4] & 0xffffu) | (vReg[5] << 16);
        wlo.w = (vReg[6] & 0xffffu) | (vReg[7] << 16);
        whi.x = (vReg[0] >> 16) | (vReg[1] & 0xffff0000u);
        whi.y = (vReg[2] >> 16) | (vReg[3] & 0xffff0000u);
        whi.z = (vReg[4] >> 16) | (vReg[5] & 0xffff0000u);
        whi.w = (vReg[6] >> 16) | (vReg[7] & 0xffff0000u);
        *(uint4*)&vt_s[nxt][vd2][vjg * 8]     = wlo;
        *(uint4*)&vt_s[nxt][vd2 + 1][vjg * 8] = whi;
    };

    stage(0, 0);
    vload(0);
    pload(0);
    __syncthreads();   // stage(0)+vload(0)+pload(0) drained; cb_s/pb_s visible

    // ---- hoisted q-fragments, pre-scaled: ac=(q+cb)*s, ap=(q+pb)*s ----
    short8 ac[2], ap[2];
    {
        const unsigned short* qrow = (const unsigned short*)q +
            ((size_t)(b * T_ + i0 + 16 * w + n16) * 512 + h64);
#pragma unroll
        for (int kc = 0; kc < 2; ++kc) {
            uint4 u = *(const uint4*)(qrow + kc * 32 + quad * 8);
            const unsigned short* uv = (const unsigned short*)&u;
            unsigned short* acp = (unsigned short*)&ac[kc];
            unsigned short* app = (unsigned short*)&ap[kc];
#pragma unroll
            for (int e = 0; e < 8; ++e) {
                int d = kc * 32 + quad * 8 + e;
                float qv = bits2f(uv[e]);
                acp[e] = fbits((qv + cb_s[d]) * sc_scale);
                app[e] = fbits((qv + pb_s[d]) * sc_scale);
            }
        }
    }
    if (i0 == 0 && t < 64) {   // wrap positional: (q_1 + pb)·p_0 (pre-scaled)
        float part = (b2f(q[(size_t)(b * T_ + 1) * 512 + h64 + t]) + pb_s[t]) *
                     b2f(p[(size_t)(b * L_) * 512 + h64 + t]);
#pragma unroll
        for (int m = 1; m < 64; m <<= 1) part += __shfl_xor(part, m, 64);
        if (t == 0) wrap_s = part * sc_scale;
    }

    // ---- loop-invariant rel-shift gather constants ----
    int srcl[4]; bool hi_[4];
#pragma unroll
    for (int r = 0; r < 4; ++r) {
        int ii = quad * 4 + r;
        srcl[r] = (lane & 48) | ((n16 - ii - 1) & 15);
        hi_[r]  = n16 > ii;
    }
    short8 onesb;   // ones-ROW A fragment: row 0 = 1 -> C[0][i] = col-sums of B
    {
        const short ov = (n16 == 0) ? (short)0x3F80 : (short)0;
#pragma unroll
        for (int e = 0; e < 8; ++e) onesb[e] = ov;
    }

    const int swzA  = (quad ^ (n16 & 7)) * 16;   // kc=0 swizzled chunk byte off
    const int swzB  = swzA ^ 64;                 // kc=1

    f32x4 O[4], O4;   // O[nt] = O^T quadrant: lane holds O[i=n16][d=nt*16+quad*4+r]
#pragma unroll
    for (int nt = 0; nt < 4; ++nt) O[nt] = (f32x4){0.f, 0.f, 0.f, 0.f};
    O4 = (f32x4){0.f, 0.f, 0.f, 0.f};

    // ---- QK: content (ac·K from LDS) + positional (ap·P from pReg) ----
    auto qk = [&](f32x4 (&Sc)[4], f32x4 (&G)[5], int buf) {
        const char* krA = (const char*)&k_s[buf][0] + n16 * 128 + swzA;
        const char* krB = (const char*)&k_s[buf][0] + n16 * 128 + swzB;
#pragma unroll
        for (int nt = 0; nt < 4; ++nt) Sc[nt] = (f32x4){0.f, 0.f, 0.f, 0.f};
#pragma unroll
        for (int ct = 0; ct < 5; ++ct) G[ct] = (f32x4){0.f, 0.f, 0.f, 0.f};
        __builtin_amdgcn_s_setprio(1);
#pragma unroll
        for (int kc = 0; kc < 2; ++kc) {
#pragma unroll
            for (int nt = 0; nt < 4; ++nt) {
                short8 bk = *(const short8*)((kc ? krB : krA) + nt * 2048);
                Sc[nt] = MFMA16(ac[kc], bk, Sc[nt]);
            }
#pragma unroll
            for (int ct = 0; ct < 5; ++ct) {
                short8 bp = *(const short8*)&pReg[kc * 5 + ct];
                G[ct] = MFMA16(ap[kc], bp, G[ct]);
            }
        }
        __builtin_amdgcn_s_setprio(0);
    };

    // ---- softmax (rel-shift gather + exp2) + transposed PV ----
    auto sm_pv = [&](const f32x4 (&Sc)[4], const f32x4 (&G)[5], int vb, bool dowrap) {
        short8 vbr[2][4];
#pragma unroll
        for (int kc = 0; kc < 2; ++kc)
#pragma unroll
            for (int nt = 0; nt < 4; ++nt)
                vbr[kc][nt] = *(const short8*)&vt_s[vb][nt * 16 + n16][kc * 32 + quad * 8];
        float pe[4][4];
#pragma unroll
        for (int r = 0; r < 4; ++r) {
            float s0 = __shfl(G[0][r], srcl[r], 64);
            float s1 = __shfl(G[1][r], srcl[r], 64);
            float s2 = __shfl(G[2][r], srcl[r], 64);
            float s3 = __shfl(G[3][r], srcl[r], 64);
            float s4 = __shfl(G[4][r], srcl[r], 64);
            pe[0][r] = Sc[0][r] + (hi_[r] ? s1 : s0);
            pe[1][r] = Sc[1][r] + (hi_[r] ? s2 : s1);
            pe[2][r] = Sc[2][r] + (hi_[r] ? s3 : s2);
            pe[3][r] = Sc[3][r] + (hi_[r] ? s4 : s3);
        }
        if (dowrap && i0 == 0 && w == 0 && lane == 15)   // wrap (i=0, j=T-1)
            pe[3][0] = Sc[3][0] + wrap_s;
#pragma unroll
        for (int ct = 0; ct < 4; ++ct)
#pragma unroll
            for (int r = 0; r < 4; ++r)
                *(bf16*)&gbuf[w][quad * 4 + r][ct * 16 + n16] = f2b(exp2f(pe[ct][r]));
        __builtin_amdgcn_s_setprio(1);
#pragma unroll
        for (int kc = 0; kc < 2; ++kc) {
            short8 pa = *(const short8*)&gbuf[w][n16][kc * 32 + quad * 8];
#pragma unroll
            for (int nt = 0; nt < 4; ++nt)
                O[nt] = MFMA16(vbr[kc][nt], pa, O[nt]);   // C[d][i] = O^T
            O4 = MFMA16(onesb, pa, O4);                   // C[0][i] = l[i]
        }
        __builtin_amdgcn_s_setprio(0);
    };

    f32x4 ScA[4], GA[5], ScB[4], GB[5];

    // ---- prologue: tile 0 staged; write V0, prefetch tile 1, compute QK_0 ----
    stage(64, 1);
    vwrite(0);                 // vt buf0 <- V tile 0 (published by next barrier)
    vload(64);
    qk(ScA, GA, 0);            // consumes pReg(tile 0)
    pload(64);                 // prefetch P for tile 1

    // ---- pipelined body: iteration tt does QK_tt and SM/PV_{tt-1} ----
    auto body = [&](int tt, f32x4 (&ScC)[4], f32x4 (&GC)[5],
                    const f32x4 (&ScP)[4], const f32x4 (&GP)[5], bool more) {
        __syncthreads();       // stage(tt)+vload(tt) drained; vwrite(tt-1) visible
        if (more) stage((tt + 1) * 64, (tt + 1) & 1);
        vwrite(tt & 1);        // vt buf[tt&1] <- V tile tt (vReg from prev iter)
        if (more) vload((tt + 1) * 64);
        qk(ScC, GC, tt & 1);           // consumes pReg(tile tt)
        if (more) pload((tt + 1) * 64);   // prefetch P for tile tt+1
        sm_pv(ScP, GP, (tt - 1) & 1, false);   // register chain from prev tile
    };

#pragma unroll
    for (int tp = 0; tp < 7; ++tp) {
        body(2 * tp + 1, ScB, GB, ScA, GA, true);
        body(2 * tp + 2, ScA, GA, ScB, GB, true);
    }
    body(15, ScB, GB, ScA, GA, false);

    // ---- drain: SM/PV for tile 15 (needs other waves' vwrite(15)) ----
    __syncthreads();
    sm_pv(ScB, GB, 1, true);

    // ---- epilogue: l[i] lives in lane i's O4[0] (quad 0 row); O^T is
    // lane-local in d -> packed 8B stores of 4 consecutive d per nt ----
    {
        float inv = 1.f / __shfl(O4[0], lane & 15, 64);
        unsigned short* orow = (unsigned short*)o +
            ((size_t)(b * T_ + i0 + 16 * w + n16) * 512 + h64);
#pragma unroll
        for (int nt = 0; nt < 4; ++nt) {
            uint2 pk;
            pk.x = (unsigned)fbits(O[nt][0] * inv) | ((unsigned)fbits(O[nt][1] * inv) << 16);
            pk.y = (unsigned)fbits(O[nt][2] * inv) | ((unsigned)fbits(O[nt][3] * inv) << 16);
            *(uint2*)(orow + nt * 16 + quad * 4) = pk;
        }
    }
}

extern "C" void kernel_launch(void* const* d_in, const int* in_sizes, int n_in,
                              void* d_out, int out_size, void* d_ws, size_t ws_size,
                              hipStream_t stream) {
    (void)in_sizes; (void)n_in; (void)out_size;
    const float* x     = (const float*)d_in[0];
    const float* pos   = (const float*)d_in[1];
    const float* cb    = (const float*)d_in[2];
    const float* pb    = (const float*)d_in[3];
    const float* gamma = (const float*)d_in[4];
    const float* beta  = (const float*)d_in[5];
    const float* Wq    = (const float*)d_in[6];
    const float* bq    = (const float*)d_in[7];
    const float* Wk    = (const float*)d_in[8];
    const float* bk    = (const float*)d_in[9];
    const float* Wv    = (const float*)d_in[10];
    const float* bv    = (const float*)d_in[11];
    const float* Wp    = (const float*)d_in[12];
    const float* Wo    = (const float*)d_in[13];
    const float* bo    = (const float*)d_in[14];
    float* out = (float*)d_out;

    const int BT = B_ * T_;       // 4096

    const size_t sz_bt = (size_t)BT * D_;            // 2,097,152
    const size_t sz_bl = (size_t)(B_ * L_) * D_;     // 4,192,256
    const size_t sz_w  = 512 * 512;
    const size_t need  = (5 * sz_bt + sz_bl + 5 * sz_w) * sizeof(bf16) + 1536 * sizeof(float);
    if (ws_size < need) return;

    // ws layout: y | o | q | k | v | p | Wqkv_t | Wp_t | Wo_t | biasq
    bf16* y       = (bf16*)d_ws;
    bf16* o       = y + sz_bt;
    bf16* q       = y + 2 * sz_bt;
    bf16* k       = y + 3 * sz_bt;
    bf16* v       = y + 4 * sz_bt;
    bf16* p       = y + 5 * sz_bt;
    bf16* Wqkv_t  = p + sz_bl;
    bf16* Wp_t    = Wqkv_t + 3 * sz_w;
    bf16* Wo_t    = Wp_t + sz_w;
    float* biasq  = (float*)(Wo_t + sz_w);
    // pos_bf scratch lives in d_out (8,388,608 B f32 region; pos_bf needs
    // 8188*512*2 = 8,384,512 B; p-GEMM OOB A-tile rows stay within the 8 MB).
    // gemm_out later overwrites every element of d_out.  attn's P reads past
    // p's end (rows <= 8253) stay inside the allocated Wqkv_t region, same as
    // the previous staged version.
    bf16* pos_bf  = (bf16*)d_out;

    prep_all<<<7429, 256, 0, stream>>>(Wq, Wk, Wv, Wp, Wo, bq, bk, bv, pos, x,
                                       gamma, beta, Wqkv_t, Wp_t, Wo_t, biasq, pos_bf, y);

    // qkv: 384 x 128x128 tiles + p: 512 x 64x128 tiles = 896 jobs
    gemm_qkvp<<<896, 256, 0, stream>>>(y, pos_bf, Wqkv_t, Wp_t, biasq, q, p, sz_bt);

    attn_mfma_kernel<<<dim3(T_ / 64, H_, B_), 256, 0, stream>>>(q, k, v, p, cb, pb, o);

    // out: [4096,512]x[512,512] + bo + x residual -> f32 d_out, 512 x 64x64 tiles
    gemm_out<<<512, 256, 0, stream>>>(o, Wo_t, bo, x, out);
}

// Round 10
// 176.175 us; speedup vs baseline: 1.1103x; 1.1103x over previous
//
#include <hip/hip_runtime.h>
#include <hip/hip_bf16.h>

typedef __hip_bfloat16 bf16;
typedef __attribute__((ext_vector_type(8))) short short8;
typedef __attribute__((ext_vector_type(4))) float f32x4;

#define B_  4
#define T_  1024
#define D_  512
#define H_  8
#define DK_ 64
#define L_  2047   // 2*T - 1

__device__ __forceinline__ float b2f(bf16 v) { return __bfloat162float(v); }
__device__ __forceinline__ bf16  f2b(float v) { return __float2bfloat16(v); }
__device__ __forceinline__ float bits2f(unsigned short u) {
    return __uint_as_float(((unsigned int)u) << 16);
}
__device__ __forceinline__ unsigned short fbits(float v) {
    bf16 h = f2b(v); return *(unsigned short*)&h;
}

#define MFMA16(a, b, c) __builtin_amdgcn_mfma_f32_16x16x32_bf16(a, b, c, 0, 0, 0)
#define GLD_LDS16(g, l) __builtin_amdgcn_global_load_lds( \
    (const __attribute__((address_space(1))) unsigned int*)(g), \
    (__attribute__((address_space(3))) unsigned int*)(l), 16, 0, 0)

// ============ prep_all: weight transpose + bias concat + pos cvt + layernorm ============
// flat grid: [0,1280) weights, [1280,1286) bias, [1286,3333) pos_cvt, [3333,7429) lnorm
__global__ __launch_bounds__(256) void prep_all(
        const float* __restrict__ Wq, const float* __restrict__ Wk,
        const float* __restrict__ Wv, const float* __restrict__ Wp,
        const float* __restrict__ Wo,
        const float* __restrict__ bq, const float* __restrict__ bk,
        const float* __restrict__ bv,
        const float* __restrict__ pos, const float* __restrict__ x,
        const float* __restrict__ gamma, const float* __restrict__ beta,
        bf16* __restrict__ Wqkv_t, bf16* __restrict__ Wp_t, bf16* __restrict__ Wo_t,
        float* __restrict__ biasq, bf16* __restrict__ pos_bf, bf16* __restrict__ y) {
    __shared__ float tl[32][33];
    __shared__ float ws1[4], ws2[4];
    const int blk = blockIdx.x;
    const int t = threadIdx.x;

    if (blk < 1280) {            // ---- weight transpose: f32 [k][n] -> bf16 [n][k] ----
        const int z = blk >> 8, rem = blk & 255;
        const float* W; bf16* Wt; int roff;
        switch (z) {
            case 0: W = Wq; Wt = Wqkv_t; roff = 0;    break;
            case 1: W = Wk; Wt = Wqkv_t; roff = 512;  break;
            case 2: W = Wv; Wt = Wqkv_t; roff = 1024; break;
            case 3: W = Wp; Wt = Wp_t;   roff = 0;    break;
            default: W = Wo; Wt = Wo_t;  roff = 0;    break;
        }
        const int n0 = (rem & 15) * 32, k0 = (rem >> 4) * 32;
        const int tx = t & 31, ty = t >> 5;
#pragma unroll
        for (int r = 0; r < 4; ++r)
            tl[ty + r * 8][tx] = W[(size_t)(k0 + ty + r * 8) * 512 + n0 + tx];
        __syncthreads();
#pragma unroll
        for (int r = 0; r < 4; ++r)
            Wt[(size_t)(roff + n0 + ty + r * 8) * 512 + k0 + tx] = f2b(tl[tx][ty + r * 8]);
    } else if (blk < 1286) {     // ---- bias concat ----
        int i = (blk - 1280) * 256 + t;
        biasq[i] = (i < 512) ? bq[i] : (i < 1024) ? bk[i - 512] : bv[i - 1024];
    } else if (blk < 3333) {     // ---- pos f32 -> bf16 ----
        size_t i = ((size_t)(blk - 1286) * 256 + t) * 8;
        float4 a = *(const float4*)(pos + i);
        float4 c = *(const float4*)(pos + i + 4);
        uint4 wv;
        wv.x = ((unsigned)fbits(a.y) << 16) | fbits(a.x);
        wv.y = ((unsigned)fbits(a.w) << 16) | fbits(a.z);
        wv.z = ((unsigned)fbits(c.y) << 16) | fbits(c.x);
        wv.w = ((unsigned)fbits(c.w) << 16) | fbits(c.z);
        *(uint4*)((unsigned short*)pos_bf + i) = wv;
    } else {                     // ---- layernorm row ----
        const int row = blk - 3333;
        const float* xr = x + (size_t)row * D_;
        float v0 = xr[t];
        float v1 = xr[t + 256];
        float s  = v0 + v1;
        float s2 = v0 * v0 + v1 * v1;
#pragma unroll
        for (int off = 32; off > 0; off >>= 1) {
            s  += __shfl_down(s,  off, 64);
            s2 += __shfl_down(s2, off, 64);
        }
        const int wid = t >> 6, lane = t & 63;
        if (!lane) { ws1[wid] = s; ws2[wid] = s2; }
        __syncthreads();
        float S  = ws1[0] + ws1[1] + ws1[2] + ws1[3];
        float S2 = ws2[0] + ws2[1] + ws2[2] + ws2[3];
        float mean = S * (1.f / D_);
        float var  = S2 * (1.f / D_) - mean * mean;
        float r = rsqrtf(var + 1e-3f);
        bf16* yr = y + (size_t)row * D_;
        yr[t]       = f2b((v0 - mean) * r * gamma[t]       + beta[t]);
        yr[t + 256] = f2b((v1 - mean) * r * gamma[t + 256] + beta[t + 256]);
    }
}

// qkv GEMM (384 blocks, 128x128) + p GEMM (512 blocks, 64x128) in one launch.
// BK=32 staging (32 KB LDS total) + launch_bounds(256,3): >=3 blocks/CU so the
// 896-block launch runs in ~1.2 occupancy rounds (BK=64's 64 KB LDS capped at
// 2 blocks/CU -> 2 full rounds).  Same ascending K-chunk accumulation order
// -> bitwise-identical q/k/v/p.  XCD-aware decode keeps A-panel L2 reuse.
__global__ __launch_bounds__(256, 3) void gemm_qkvp(
        const bf16* __restrict__ y, const bf16* __restrict__ pos_bf,
        const bf16* __restrict__ Wqkv_t, const bf16* __restrict__ Wp_t,
        const float* __restrict__ biasq,
        bf16* __restrict__ q, bf16* __restrict__ p, size_t seg_elems) {
    __shared__ __align__(16) unsigned short A_s[256][32];   // 2 bufs x 128 rows
    __shared__ __align__(16) unsigned short B_s[256][32];
    const int gid = blockIdx.x;
    const int t = threadIdx.x;
    const int w = t >> 6, lane = t & 63;
    const int quad = lane >> 4, n16 = lane & 15;
    const int ar = lane >> 2, ac8 = (lane & 3) * 8;

    if (gid < 384) {
        // ---- qkv: [4096,512] x [512,1536], 128x128 tiles, BK=32 ----
        const int xcd = gid & 7, s = gid >> 3;       // s: 0..47
        const int n0 = (s % 12) * 128;
        const int m0 = (xcd * 4 + s / 12) * 128;     // 0..31 m-tiles
        const int wm = (w >> 1) * 64, wn = (w & 1) * 64;

        f32x4 acc[4][4];
#pragma unroll
        for (int a = 0; a < 4; ++a)
#pragma unroll
            for (int b = 0; b < 4; ++b) acc[a][b] = (f32x4){0.f, 0.f, 0.f, 0.f};

        auto stage = [&](int k0, int buf) {
            const int bo = buf << 7;
#pragma unroll
            for (int ps = 0; ps < 2; ++ps) {
                int br = (ps * 4 + w) * 16;
                GLD_LDS16(y      + (size_t)(m0 + br + ar) * 512 + k0 + ac8, &A_s[bo + br][0]);
                GLD_LDS16(Wqkv_t + (size_t)(n0 + br + ar) * 512 + k0 + ac8, &B_s[bo + br][0]);
            }
        };
        stage(0, 0);
        int cur = 0;
        for (int k0 = 0; k0 < 512; k0 += 32) {
            __syncthreads();
            if (k0 + 32 < 512) stage(k0 + 32, cur ^ 1);
            const int bo = cur << 7;
            short8 af[4], bfr[4];
#pragma unroll
            for (int i = 0; i < 4; ++i) {
                af[i]  = *(const short8*)&A_s[bo + wm + i * 16 + n16][quad * 8];
                bfr[i] = *(const short8*)&B_s[bo + wn + i * 16 + n16][quad * 8];
            }
#pragma unroll
            for (int mi = 0; mi < 4; ++mi)
#pragma unroll
                for (int ni = 0; ni < 4; ++ni)
                    acc[mi][ni] = MFMA16(af[mi], bfr[ni], acc[mi][ni]);
            cur ^= 1;
        }
        const int seg = n0 >> 9;
#pragma unroll
        for (int mi = 0; mi < 4; ++mi) {
#pragma unroll
            for (int r = 0; r < 4; ++r) {
                int row = m0 + wm + mi * 16 + quad * 4 + r;
#pragma unroll
                for (int ni = 0; ni < 4; ++ni) {
                    int col  = n0 + wn + ni * 16 + n16;
                    int coll = col & 511;
                    bf16* Cp = q + seg * seg_elems;
                    Cp[(size_t)row * 512 + coll] = f2b(acc[mi][ni][r] + biasq[col]);
                }
            }
        }
    } else {
        // ---- p: [8188,512] x [512,512], 64x128 tiles, BK=32 ----
        const int g2 = gid - 384;                    // 0..511 (384%8==0)
        const int xcd = g2 & 7, s = g2 >> 3;         // s: 0..63
        const int n0 = (s & 3) * 128;
        const int m0 = (xcd * 16 + (s >> 2)) * 64;   // 128 m-tiles of 64 rows
        const int wm = (w >> 1) * 32, wn = (w & 1) * 64;

        f32x4 acc[2][4];
#pragma unroll
        for (int a = 0; a < 2; ++a)
#pragma unroll
            for (int b = 0; b < 4; ++b) acc[a][b] = (f32x4){0.f, 0.f, 0.f, 0.f};

        // A loads for rows up to 8191 stay inside pos_bf's 8 MB d_out region
        // (8192*1024B == d_out size); stores are M-guarded.
        auto stage = [&](int k0, int buf) {
            const int boA = buf * 64, boB = buf * 128;
            GLD_LDS16(pos_bf + (size_t)(m0 + w * 16 + ar) * 512 + k0 + ac8,
                      &A_s[boA + w * 16][0]);
#pragma unroll
            for (int ps = 0; ps < 2; ++ps)
                GLD_LDS16(Wp_t + (size_t)(n0 + (ps * 4 + w) * 16 + ar) * 512 + k0 + ac8,
                          &B_s[boB + (ps * 4 + w) * 16][0]);
        };
        stage(0, 0);
        int cur = 0;
        for (int k0 = 0; k0 < 512; k0 += 32) {
            __syncthreads();
            if (k0 + 32 < 512) stage(k0 + 32, cur ^ 1);
            const int boA = cur * 64, boB = cur * 128;
            short8 af[2], bfr[4];
#pragma unroll
            for (int i = 0; i < 2; ++i)
                af[i] = *(const short8*)&A_s[boA + wm + i * 16 + n16][quad * 8];
#pragma unroll
            for (int i = 0; i < 4; ++i)
                bfr[i] = *(const short8*)&B_s[boB + wn + i * 16 + n16][quad * 8];
#pragma unroll
            for (int mi = 0; mi < 2; ++mi)
#pragma unroll
                for (int ni = 0; ni < 4; ++ni)
                    acc[mi][ni] = MFMA16(af[mi], bfr[ni], acc[mi][ni]);
            cur ^= 1;
        }
#pragma unroll
        for (int mi = 0; mi < 2; ++mi) {
#pragma unroll
            for (int r = 0; r < 4; ++r) {
                int row = m0 + wm + mi * 16 + quad * 4 + r;
                if (row >= 8188) continue;
#pragma unroll
                for (int ni = 0; ni < 4; ++ni) {
                    int col = n0 + wn + ni * 16 + n16;
                    p[(size_t)row * 512 + col] = f2b(acc[mi][ni][r]);
                }
            }
        }
    }
}

// out-projection: 64x64 tiles -> 512 blocks (2/CU, full machine), BK=64
// (8 barrier-drains).  acc + bias + residual fused, f32 store.  XCD m-grouping.
__global__ __launch_bounds__(256) void gemm_out(
        const bf16* __restrict__ o, const bf16* __restrict__ Wo_t,
        const float* __restrict__ bo, const float* __restrict__ x,
        float* __restrict__ out) {
    __shared__ __align__(16) unsigned short A_s[256][32];   // 2 bufs x 2 kc x 64 rows
    __shared__ __align__(16) unsigned short B_s[256][32];
    const int gid = blockIdx.x;                     // 0..511
    const int xcd = gid & 7, s = gid >> 3;          // s: 0..63
    const int n0 = (s & 7) * 64;
    const int m0 = (xcd * 8 + (s >> 3)) * 64;       // 64 m-tiles of 64 rows
    const int t = threadIdx.x;
    const int w = t >> 6, lane = t & 63;
    const int quad = lane >> 4, n16 = lane & 15;
    const int wm = (w >> 1) * 32, wn = (w & 1) * 32;

    f32x4 acc[2][2];
#pragma unroll
    for (int a = 0; a < 2; ++a)
#pragma unroll
        for (int b = 0; b < 2; ++b) acc[a][b] = (f32x4){0.f, 0.f, 0.f, 0.f};

    const int ar = lane >> 2, ac8 = (lane & 3) * 8;
    auto stage = [&](int k0, int buf) {
        const int bo = buf * 128;
#pragma unroll
        for (int kc = 0; kc < 2; ++kc) {
            GLD_LDS16(o    + (size_t)(m0 + w * 16 + ar) * 512 + k0 + kc * 32 + ac8,
                      &A_s[bo + kc * 64 + w * 16][0]);
            GLD_LDS16(Wo_t + (size_t)(n0 + w * 16 + ar) * 512 + k0 + kc * 32 + ac8,
                      &B_s[bo + kc * 64 + w * 16][0]);
        }
    };
    stage(0, 0);
    int cur = 0;
    for (int k0 = 0; k0 < 512; k0 += 64) {
        __syncthreads();
        if (k0 + 64 < 512) stage(k0 + 64, cur ^ 1);
        const int bo = cur * 128;
#pragma unroll
        for (int kc = 0; kc < 2; ++kc) {
            short8 af[2], bfr[2];
#pragma unroll
            for (int i = 0; i < 2; ++i) {
                af[i]  = *(const short8*)&A_s[bo + kc * 64 + wm + i * 16 + n16][quad * 8];
                bfr[i] = *(const short8*)&B_s[bo + kc * 64 + wn + i * 16 + n16][quad * 8];
            }
#pragma unroll
            for (int mi = 0; mi < 2; ++mi)
#pragma unroll
                for (int ni = 0; ni < 2; ++ni)
                    acc[mi][ni] = MFMA16(af[mi], bfr[ni], acc[mi][ni]);
        }
        cur ^= 1;
    }
#pragma unroll
    for (int mi = 0; mi < 2; ++mi) {
#pragma unroll
        for (int r = 0; r < 4; ++r) {
            int row = m0 + wm + mi * 16 + quad * 4 + r;
#pragma unroll
            for (int ni = 0; ni < 2; ++ni) {
                int col = n0 + wn + ni * 16 + n16;
                out[(size_t)row * 512 + col] =
                    acc[mi][ni][r] + bo[col] + x[(size_t)row * 512 + col];
            }
        }
    }
}

// ============ Fused MFMA flash attention, v8 (reverted from v9) ============
// R8's proven structure: pw_s gl_lds staging restored (R9's P-from-global
// gather serialized the TA path: 10 loads x 16 distinct cache lines each ->
// attn 43 -> 90 us).  Pipeline QK_t || SM/PV_{t-1}, one barrier/tile,
// setprio, O^T operand-swap PV, packed 8B epilogue.
__global__ __launch_bounds__(256, 2) void attn_mfma_kernel(
        const bf16* __restrict__ q, const bf16* __restrict__ k,
        const bf16* __restrict__ v, const bf16* __restrict__ p,
        const float* __restrict__ cbias, const float* __restrict__ pbias,
        bf16* __restrict__ o) {
    __shared__ __align__(16) unsigned short k_s[2][4096];     // 64 rows x 64
    __shared__ __align__(16) unsigned short pw_s[2][8192];    // 128 rows x 64
    __shared__ __align__(16) unsigned short vt_s[2][64][72];  // V^T [d][j], padded
    __shared__ __align__(16) unsigned short gbuf[4][16][72];  // P tile per wave
    __shared__ float cb_s[64], pb_s[64];
    __shared__ float wrap_s;

    const int i0 = blockIdx.x * 64;
    const int h  = blockIdx.y;
    const int b  = blockIdx.z;
    const int t  = threadIdx.x;
    const int w    = t >> 6;
    const int lane = t & 63;
    const int quad = lane >> 4;
    const int n16  = lane & 15;
    const int h64  = h * 64;
    const float sc_scale = 0.125f * 1.4426950408889634f;   // (1/8)*log2(e)

    if (t < 64)       cb_s[t]      = cbias[h64 + t];
    else if (t < 128) pb_s[t - 64] = pbias[h64 + t - 64];

    // ---- per-lane staging sources (inverse-swizzled global addresses) ----
    const int l8 = lane >> 3, l7 = lane & 7;
    const int clog8 = (l7 ^ l8) * 8;          // logical chunk for this lane's LDS slot
    const unsigned short* ksrc[2];
    const unsigned short* psrc[4];
#pragma unroll
    for (int ps = 0; ps < 2; ++ps) {
        int row = (w * 2 + ps) * 8 + l8;
        ksrc[ps] = (const unsigned short*)k + ((size_t)(b * T_ + row) * 512 + h64 + clog8);
    }
    const int slb = T_ - i0 - 63;             // p row for pw_s row 0 at j0=0 (>=1)
#pragma unroll
    for (int ps = 0; ps < 4; ++ps) {
        int row = (w * 4 + ps) * 8 + l8;
        psrc[ps] = (const unsigned short*)p + ((size_t)(b * L_ + slb + row) * 512 + h64 + clog8);
    }
    auto stage = [&](int j0n, int nxt) {
        size_t joff = (size_t)j0n * 512;
#pragma unroll
        for (int ps = 0; ps < 2; ++ps)
            GLD_LDS16(ksrc[ps] + joff, &k_s[nxt][(w * 2 + ps) * 512]);
#pragma unroll
        for (int ps = 0; ps < 4; ++ps)
            GLD_LDS16(psrc[ps] + joff, &pw_s[nxt][(w * 4 + ps) * 512]);
    };

    // ---- V: reg-staged transpose (needs scatter, so no global_load_lds) ----
    const int vd2 = (t & 31) * 2, vjg = t >> 5;
    const unsigned short* vsrc = (const unsigned short*)v +
        ((size_t)(b * T_ + vjg * 8) * 512 + h64 + vd2);
    unsigned int vReg[8];
    auto vload = [&](int j0n) {
        const unsigned short* vg = vsrc + (size_t)j0n * 512;
#pragma unroll
        for (int e = 0; e < 8; ++e) vReg[e] = *(const unsigned int*)(vg + (size_t)e * 512);
    };
    auto vwrite = [&](int nxt) {
        uint4 wlo, whi;
        wlo.x = (vReg[0] & 0xffffu) | (vReg[1] << 16);
        wlo.y = (vReg[2] & 0xffffu) | (vReg[3] << 16);
        wlo.z = (vReg[4] & 0xffffu) | (vReg[5] << 16);
        wlo.w = (vReg[6] & 0xffffu) | (vReg[7] << 16);
        whi.x = (vReg[0] >> 16) | (vReg[1] & 0xffff0000u);
        whi.y = (vReg[2] >> 16) | (vReg[3] & 0xffff0000u);
        whi.z = (vReg[4] >> 16) | (vReg[5] & 0xffff0000u);
        whi.w = (vReg[6] >> 16) | (vReg[7] & 0xffff0000u);
        *(uint4*)&vt_s[nxt][vd2][vjg * 8]     = wlo;
        *(uint4*)&vt_s[nxt][vd2 + 1][vjg * 8] = whi;
    };

    stage(0, 0);
    vload(0);
    __syncthreads();   // stage(0)+vload(0) drained; cb_s/pb_s visible

    // ---- hoisted q-fragments, pre-scaled: ac=(q+cb)*s, ap=(q+pb)*s ----
    short8 ac[2], ap[2];
    {
        const unsigned short* qrow = (const unsigned short*)q +
            ((size_t)(b * T_ + i0 + 16 * w + n16) * 512 + h64);
#pragma unroll
        for (int kc = 0; kc < 2; ++kc) {
            uint4 u = *(const uint4*)(qrow + kc * 32 + quad * 8);
            const unsigned short* uv = (const unsigned short*)&u;
            unsigned short* acp = (unsigned short*)&ac[kc];
            unsigned short* app = (unsigned short*)&ap[kc];
#pragma unroll
            for (int e = 0; e < 8; ++e) {
                int d = kc * 32 + quad * 8 + e;
                float qv = bits2f(uv[e]);
                acp[e] = fbits((qv + cb_s[d]) * sc_scale);
                app[e] = fbits((qv + pb_s[d]) * sc_scale);
            }
        }
    }
    if (i0 == 0 && t < 64) {   // wrap positional: (q_1 + pb)·p_0 (pre-scaled)
        float part = (b2f(q[(size_t)(b * T_ + 1) * 512 + h64 + t]) + pb_s[t]) *
                     b2f(p[(size_t)(b * L_) * 512 + h64 + t]);
#pragma unroll
        for (int m = 1; m < 64; m <<= 1) part += __shfl_xor(part, m, 64);
        if (t == 0) wrap_s = part * sc_scale;
    }

    // ---- loop-invariant rel-shift gather constants ----
    int srcl[4]; bool hi_[4];
#pragma unroll
    for (int r = 0; r < 4; ++r) {
        int ii = quad * 4 + r;
        srcl[r] = (lane & 48) | ((n16 - ii - 1) & 15);
        hi_[r]  = n16 > ii;
    }
    short8 onesb;   // ones-ROW A fragment: row 0 = 1 -> C[0][i] = col-sums of B
    {
        const short ov = (n16 == 0) ? (short)0x3F80 : (short)0;
#pragma unroll
        for (int e = 0; e < 8; ++e) onesb[e] = ov;
    }

    const int pwoff = 48 - 16 * w;
    const int swzA  = (quad ^ (n16 & 7)) * 16;   // kc=0 swizzled chunk byte off
    const int swzB  = swzA ^ 64;                 // kc=1

    f32x4 O[4], O4;   // O[nt] = O^T quadrant: lane holds O[i=n16][d=nt*16+quad*4+r]
#pragma unroll
    for (int nt = 0; nt < 4; ++nt) O[nt] = (f32x4){0.f, 0.f, 0.f, 0.f};
    O4 = (f32x4){0.f, 0.f, 0.f, 0.f};

    // ---- QK: content (ac·K) + positional window (ap·P) for LDS buf ----
    auto qk = [&](f32x4 (&Sc)[4], f32x4 (&G)[5], int buf) {
        const char* krA  = (const char*)&k_s[buf][0]  + n16 * 128 + swzA;
        const char* krB  = (const char*)&k_s[buf][0]  + n16 * 128 + swzB;
        const char* pwrA = (const char*)&pw_s[buf][0] + (pwoff + n16) * 128 + swzA;
        const char* pwrB = (const char*)&pw_s[buf][0] + (pwoff + n16) * 128 + swzB;
#pragma unroll
        for (int nt = 0; nt < 4; ++nt) Sc[nt] = (f32x4){0.f, 0.f, 0.f, 0.f};
#pragma unroll
        for (int ct = 0; ct < 5; ++ct) G[ct] = (f32x4){0.f, 0.f, 0.f, 0.f};
        __builtin_amdgcn_s_setprio(1);
#pragma unroll
        for (int kc = 0; kc < 2; ++kc) {
#pragma unroll
            for (int nt = 0; nt < 4; ++nt) {
                short8 bk = *(const short8*)((kc ? krB : krA) + nt * 2048);
                Sc[nt] = MFMA16(ac[kc], bk, Sc[nt]);
            }
#pragma unroll
            for (int ct = 0; ct < 5; ++ct) {
                short8 bp = *(const short8*)((kc ? pwrB : pwrA) + ct * 2048);
                G[ct] = MFMA16(ap[kc], bp, G[ct]);
            }
        }
        __builtin_amdgcn_s_setprio(0);
    };

    // ---- softmax (rel-shift gather + exp2) + transposed PV ----
    auto sm_pv = [&](const f32x4 (&Sc)[4], const f32x4 (&G)[5], int vb, bool dowrap) {
        short8 vbr[2][4];
#pragma unroll
        for (int kc = 0; kc < 2; ++kc)
#pragma unroll
            for (int nt = 0; nt < 4; ++nt)
                vbr[kc][nt] = *(const short8*)&vt_s[vb][nt * 16 + n16][kc * 32 + quad * 8];
        float pe[4][4];
#pragma unroll
        for (int r = 0; r < 4; ++r) {
            float s0 = __shfl(G[0][r], srcl[r], 64);
            float s1 = __shfl(G[1][r], srcl[r], 64);
            float s2 = __shfl(G[2][r], srcl[r], 64);
            float s3 = __shfl(G[3][r], srcl[r], 64);
            float s4 = __shfl(G[4][r], srcl[r], 64);
            pe[0][r] = Sc[0][r] + (hi_[r] ? s1 : s0);
            pe[1][r] = Sc[1][r] + (hi_[r] ? s2 : s1);
            pe[2][r] = Sc[2][r] + (hi_[r] ? s3 : s2);
            pe[3][r] = Sc[3][r] + (hi_[r] ? s4 : s3);
        }
        if (dowrap && i0 == 0 && w == 0 && lane == 15)   // wrap (i=0, j=T-1)
            pe[3][0] = Sc[3][0] + wrap_s;
#pragma unroll
        for (int ct = 0; ct < 4; ++ct)
#pragma unroll
            for (int r = 0; r < 4; ++r)
                *(bf16*)&gbuf[w][quad * 4 + r][ct * 16 + n16] = f2b(exp2f(pe[ct][r]));
        __builtin_amdgcn_s_setprio(1);
#pragma unroll
        for (int kc = 0; kc < 2; ++kc) {
            short8 pa = *(const short8*)&gbuf[w][n16][kc * 32 + quad * 8];
#pragma unroll
            for (int nt = 0; nt < 4; ++nt)
                O[nt] = MFMA16(vbr[kc][nt], pa, O[nt]);   // C[d][i] = O^T
            O4 = MFMA16(onesb, pa, O4);                   // C[0][i] = l[i]
        }
        __builtin_amdgcn_s_setprio(0);
    };

    f32x4 ScA[4], GA[5], ScB[4], GB[5];

    // ---- prologue: tile 0 staged; write V0, prefetch tile 1, compute QK_0 ----
    stage(64, 1);
    vwrite(0);                 // vt buf0 <- V tile 0 (published by next barrier)
    vload(64);
    qk(ScA, GA, 0);

    // ---- pipelined body: iteration tt does QK_tt and SM/PV_{tt-1} ----
    auto body = [&](int tt, f32x4 (&ScC)[4], f32x4 (&GC)[5],
                    const f32x4 (&ScP)[4], const f32x4 (&GP)[5], bool more) {
        __syncthreads();       // stage(tt)+vload(tt) drained; vwrite(tt-1) visible
        if (more) stage((tt + 1) * 64, (tt + 1) & 1);
        vwrite(tt & 1);        // vt buf[tt&1] <- V tile tt (vReg from prev iter)
        if (more) vload((tt + 1) * 64);
        qk(ScC, GC, tt & 1);           // independent MFMA stream
        sm_pv(ScP, GP, (tt - 1) & 1, false);   // register chain from prev tile
    };

#pragma unroll
    for (int tp = 0; tp < 7; ++tp) {
        body(2 * tp + 1, ScB, GB, ScA, GA, true);
        body(2 * tp + 2, ScA, GA, ScB, GB, true);
    }
    body(15, ScB, GB, ScA, GA, false);

    // ---- drain: SM/PV for tile 15 (needs other waves' vwrite(15)) ----
    __syncthreads();
    sm_pv(ScB, GB, 1, true);

    // ---- epilogue: l[i] lives in lane i's O4[0] (quad 0 row); O^T is
    // lane-local in d -> packed 8B stores of 4 consecutive d per nt ----
    {
        float inv = 1.f / __shfl(O4[0], lane & 15, 64);
        unsigned short* orow = (unsigned short*)o +
            ((size_t)(b * T_ + i0 + 16 * w + n16) * 512 + h64);
#pragma unroll
        for (int nt = 0; nt < 4; ++nt) {
            uint2 pk;
            pk.x = (unsigned)fbits(O[nt][0] * inv) | ((unsigned)fbits(O[nt][1] * inv) << 16);
            pk.y = (unsigned)fbits(O[nt][2] * inv) | ((unsigned)fbits(O[nt][3] * inv) << 16);
            *(uint2*)(orow + nt * 16 + quad * 4) = pk;
        }
    }
}

extern "C" void kernel_launch(void* const* d_in, const int* in_sizes, int n_in,
                              void* d_out, int out_size, void* d_ws, size_t ws_size,
                              hipStream_t stream) {
    (void)in_sizes; (void)n_in; (void)out_size;
    const float* x     = (const float*)d_in[0];
    const float* pos   = (const float*)d_in[1];
    const float* cb    = (const float*)d_in[2];
    const float* pb    = (const float*)d_in[3];
    const float* gamma = (const float*)d_in[4];
    const float* beta  = (const float*)d_in[5];
    const float* Wq    = (const float*)d_in[6];
    const float* bq    = (const float*)d_in[7];
    const float* Wk    = (const float*)d_in[8];
    const float* bk    = (const float*)d_in[9];
    const float* Wv    = (const float*)d_in[10];
    const float* bv    = (const float*)d_in[11];
    const float* Wp    = (const float*)d_in[12];
    const float* Wo    = (const float*)d_in[13];
    const float* bo    = (const float*)d_in[14];
    float* out = (float*)d_out;

    const int BT = B_ * T_;       // 4096

    const size_t sz_bt = (size_t)BT * D_;            // 2,097,152
    const size_t sz_bl = (size_t)(B_ * L_) * D_;     // 4,192,256
    const size_t sz_w  = 512 * 512;
    const size_t need  = (5 * sz_bt + sz_bl + 5 * sz_w) * sizeof(bf16) + 1536 * sizeof(float);
    if (ws_size < need) return;

    // ws layout: y | o | q | k | v | p | Wqkv_t | Wp_t | Wo_t | biasq
    bf16* y       = (bf16*)d_ws;
    bf16* o       = y + sz_bt;
    bf16* q       = y + 2 * sz_bt;
    bf16* k       = y + 3 * sz_bt;
    bf16* v       = y + 4 * sz_bt;
    bf16* p       = y + 5 * sz_bt;
    bf16* Wqkv_t  = p + sz_bl;
    bf16* Wp_t    = Wqkv_t + 3 * sz_w;
    bf16* Wo_t    = Wp_t + sz_w;
    float* biasq  = (float*)(Wo_t + sz_w);
    // pos_bf scratch lives in d_out (8,388,608 B f32 region; pos_bf needs
    // 8188*512*2 = 8,384,512 B; p-GEMM OOB A-tile rows stay within the 8 MB).
    // gemm_out later overwrites every element of d_out.
    bf16* pos_bf  = (bf16*)d_out;

    prep_all<<<7429, 256, 0, stream>>>(Wq, Wk, Wv, Wp, Wo, bq, bk, bv, pos, x,
                                       gamma, beta, Wqkv_t, Wp_t, Wo_t, biasq, pos_bf, y);

    // qkv: 384 x 128x128 tiles + p: 512 x 64x128 tiles = 896 jobs, BK=32
    gemm_qkvp<<<896, 256, 0, stream>>>(y, pos_bf, Wqkv_t, Wp_t, biasq, q, p, sz_bt);

    attn_mfma_kernel<<<dim3(T_ / 64, H_, B_), 256, 0, stream>>>(q, k, v, p, cb, pb, o);

    // out: [4096,512]x[512,512] + bo + x residual -> f32 d_out, 512 x 64x64 tiles
    gemm_out<<<512, 256, 0, stream>>>(o, Wo_t, bo, x, out);
}

// Round 11
// 173.171 us; speedup vs baseline: 1.1296x; 1.0173x over previous
//
#include <hip/hip_runtime.h>
#include <hip/hip_bf16.h>

typedef __hip_bfloat16 bf16;
typedef __attribute__((ext_vector_type(8))) short short8;
typedef __attribute__((ext_vector_type(4))) float f32x4;

#define B_  4
#define T_  1024
#define D_  512
#define H_  8
#define DK_ 64
#define L_  2047   // 2*T - 1

__device__ __forceinline__ float b2f(bf16 v) { return __bfloat162float(v); }
__device__ __forceinline__ bf16  f2b(float v) { return __float2bfloat16(v); }
__device__ __forceinline__ float bits2f(unsigned short u) {
    return __uint_as_float(((unsigned int)u) << 16);
}
__device__ __forceinline__ unsigned short fbits(float v) {
    bf16 h = f2b(v); return *(unsigned short*)&h;
}

#define MFMA16(a, b, c) __builtin_amdgcn_mfma_f32_16x16x32_bf16(a, b, c, 0, 0, 0)
#define GLD_LDS16(g, l) __builtin_amdgcn_global_load_lds( \
    (const __attribute__((address_space(1))) unsigned int*)(g), \
    (__attribute__((address_space(3))) unsigned int*)(l), 16, 0, 0)

// ============ prep_all: weight transpose + bias concat + pos cvt + layernorm ============
// flat grid: [0,1280) weights, [1280,1286) bias, [1286,3333) pos_cvt, [3333,7429) lnorm
__global__ __launch_bounds__(256) void prep_all(
        const float* __restrict__ Wq, const float* __restrict__ Wk,
        const float* __restrict__ Wv, const float* __restrict__ Wp,
        const float* __restrict__ Wo,
        const float* __restrict__ bq, const float* __restrict__ bk,
        const float* __restrict__ bv,
        const float* __restrict__ pos, const float* __restrict__ x,
        const float* __restrict__ gamma, const float* __restrict__ beta,
        bf16* __restrict__ Wqkv_t, bf16* __restrict__ Wp_t, bf16* __restrict__ Wo_t,
        float* __restrict__ biasq, bf16* __restrict__ pos_bf, bf16* __restrict__ y) {
    __shared__ float tl[32][33];
    __shared__ float ws1[4], ws2[4];
    const int blk = blockIdx.x;
    const int t = threadIdx.x;

    if (blk < 1280) {            // ---- weight transpose: f32 [k][n] -> bf16 [n][k] ----
        const int z = blk >> 8, rem = blk & 255;
        const float* W; bf16* Wt; int roff;
        switch (z) {
            case 0: W = Wq; Wt = Wqkv_t; roff = 0;    break;
            case 1: W = Wk; Wt = Wqkv_t; roff = 512;  break;
            case 2: W = Wv; Wt = Wqkv_t; roff = 1024; break;
            case 3: W = Wp; Wt = Wp_t;   roff = 0;    break;
            default: W = Wo; Wt = Wo_t;  roff = 0;    break;
        }
        const int n0 = (rem & 15) * 32, k0 = (rem >> 4) * 32;
        const int tx = t & 31, ty = t >> 5;
#pragma unroll
        for (int r = 0; r < 4; ++r)
            tl[ty + r * 8][tx] = W[(size_t)(k0 + ty + r * 8) * 512 + n0 + tx];
        __syncthreads();
#pragma unroll
        for (int r = 0; r < 4; ++r)
            Wt[(size_t)(roff + n0 + ty + r * 8) * 512 + k0 + tx] = f2b(tl[tx][ty + r * 8]);
    } else if (blk < 1286) {     // ---- bias concat ----
        int i = (blk - 1280) * 256 + t;
        biasq[i] = (i < 512) ? bq[i] : (i < 1024) ? bk[i - 512] : bv[i - 1024];
    } else if (blk < 3333) {     // ---- pos f32 -> bf16 ----
        size_t i = ((size_t)(blk - 1286) * 256 + t) * 8;
        float4 a = *(const float4*)(pos + i);
        float4 c = *(const float4*)(pos + i + 4);
        uint4 wv;
        wv.x = ((unsigned)fbits(a.y) << 16) | fbits(a.x);
        wv.y = ((unsigned)fbits(a.w) << 16) | fbits(a.z);
        wv.z = ((unsigned)fbits(c.y) << 16) | fbits(c.x);
        wv.w = ((unsigned)fbits(c.w) << 16) | fbits(c.z);
        *(uint4*)((unsigned short*)pos_bf + i) = wv;
    } else {                     // ---- layernorm row ----
        const int row = blk - 3333;
        const float* xr = x + (size_t)row * D_;
        float v0 = xr[t];
        float v1 = xr[t + 256];
        float s  = v0 + v1;
        float s2 = v0 * v0 + v1 * v1;
#pragma unroll
        for (int off = 32; off > 0; off >>= 1) {
            s  += __shfl_down(s,  off, 64);
            s2 += __shfl_down(s2, off, 64);
        }
        const int wid = t >> 6, lane = t & 63;
        if (!lane) { ws1[wid] = s; ws2[wid] = s2; }
        __syncthreads();
        float S  = ws1[0] + ws1[1] + ws1[2] + ws1[3];
        float S2 = ws2[0] + ws2[1] + ws2[2] + ws2[3];
        float mean = S * (1.f / D_);
        float var  = S2 * (1.f / D_) - mean * mean;
        float r = rsqrtf(var + 1e-3f);
        bf16* yr = y + (size_t)row * D_;
        yr[t]       = f2b((v0 - mean) * r * gamma[t]       + beta[t]);
        yr[t + 256] = f2b((v1 - mean) * r * gamma[t + 256] + beta[t + 256]);
    }
}

// qkv GEMM (768 blocks, 64x128) + p GEMM (512 blocks, 64x128) in one launch.
// UNIFORM 64x128 tiles: all 1280 jobs are equal half-duration blocks with
// acc[2][4] (~80 VGPR) + 24 KB LDS -> launch_bounds(256,4) = 4 blocks/CU,
// 1024 co-resident, ~1.25 uniform rounds (was 384 big + 512 half blocks at
// <=3/CU with ragged makespan).  Ascending BK=32 K-order is unchanged ->
// bitwise-identical q/k/v/p.  XCD-aware decode keeps A-panel L2 reuse.
__global__ __launch_bounds__(256, 4) void gemm_qkvp(
        const bf16* __restrict__ y, const bf16* __restrict__ pos_bf,
        const bf16* __restrict__ Wqkv_t, const bf16* __restrict__ Wp_t,
        const float* __restrict__ biasq,
        bf16* __restrict__ q, bf16* __restrict__ p, size_t seg_elems) {
    __shared__ __align__(16) unsigned short A_s[128][32];   // 2 bufs x 64 rows
    __shared__ __align__(16) unsigned short B_s[256][32];   // 2 bufs x 128 rows
    const int gid = blockIdx.x;
    const int t = threadIdx.x;
    const int w = t >> 6, lane = t & 63;
    const int quad = lane >> 4, n16 = lane & 15;
    const int ar = lane >> 2, ac8 = (lane & 3) * 8;
    const int wm = (w >> 1) * 32, wn = (w & 1) * 64;

    const bf16* A; const bf16* Bw; int m0, n0; bool isqkv;
    if (gid < 768) {
        // ---- qkv: [4096,512] x [512,1536], 64x128 tiles ----
        const int xcd = gid & 7, s = gid >> 3;       // s: 0..95
        n0 = (s % 12) * 128;
        m0 = (xcd * 8 + s / 12) * 64;                // 64 m-tiles of 64 rows
        A = y; Bw = Wqkv_t; isqkv = true;
    } else {
        // ---- p: [8188,512] x [512,512], 64x128 tiles ----
        const int g2 = gid - 768;                    // 0..511 (768%8==0)
        const int xcd = g2 & 7, s = g2 >> 3;         // s: 0..63
        n0 = (s & 3) * 128;
        m0 = (xcd * 16 + (s >> 2)) * 64;             // 128 m-tiles of 64 rows
        A = pos_bf; Bw = Wp_t; isqkv = false;
        // A loads for rows up to 8191 stay inside pos_bf's 8 MB d_out region
        // (8192*1024B == d_out size); stores are M-guarded.
    }

    f32x4 acc[2][4];
#pragma unroll
    for (int a = 0; a < 2; ++a)
#pragma unroll
        for (int b = 0; b < 4; ++b) acc[a][b] = (f32x4){0.f, 0.f, 0.f, 0.f};

    auto stage = [&](int k0, int buf) {
        const int boA = buf * 64, boB = buf * 128;
        GLD_LDS16(A + (size_t)(m0 + w * 16 + ar) * 512 + k0 + ac8,
                  &A_s[boA + w * 16][0]);
#pragma unroll
        for (int ps = 0; ps < 2; ++ps)
            GLD_LDS16(Bw + (size_t)(n0 + (ps * 4 + w) * 16 + ar) * 512 + k0 + ac8,
                      &B_s[boB + (ps * 4 + w) * 16][0]);
    };
    stage(0, 0);
    int cur = 0;
    for (int k0 = 0; k0 < 512; k0 += 32) {
        __syncthreads();
        if (k0 + 32 < 512) stage(k0 + 32, cur ^ 1);
        const int boA = cur * 64, boB = cur * 128;
        short8 af[2], bfr[4];
#pragma unroll
        for (int i = 0; i < 2; ++i)
            af[i] = *(const short8*)&A_s[boA + wm + i * 16 + n16][quad * 8];
#pragma unroll
        for (int i = 0; i < 4; ++i)
            bfr[i] = *(const short8*)&B_s[boB + wn + i * 16 + n16][quad * 8];
#pragma unroll
        for (int mi = 0; mi < 2; ++mi)
#pragma unroll
            for (int ni = 0; ni < 4; ++ni)
                acc[mi][ni] = MFMA16(af[mi], bfr[ni], acc[mi][ni]);
        cur ^= 1;
    }

    if (isqkv) {
#pragma unroll
        for (int mi = 0; mi < 2; ++mi) {
#pragma unroll
            for (int r = 0; r < 4; ++r) {
                int row = m0 + wm + mi * 16 + quad * 4 + r;
#pragma unroll
                for (int ni = 0; ni < 4; ++ni) {
                    int col  = n0 + wn + ni * 16 + n16;
                    int coll = col & 511;
                    bf16* Cp = q + (size_t)(col >> 9) * seg_elems;
                    Cp[(size_t)row * 512 + coll] = f2b(acc[mi][ni][r] + biasq[col]);
                }
            }
        }
    } else {
#pragma unroll
        for (int mi = 0; mi < 2; ++mi) {
#pragma unroll
            for (int r = 0; r < 4; ++r) {
                int row = m0 + wm + mi * 16 + quad * 4 + r;
                if (row >= 8188) continue;
#pragma unroll
                for (int ni = 0; ni < 4; ++ni) {
                    int col = n0 + wn + ni * 16 + n16;
                    p[(size_t)row * 512 + col] = f2b(acc[mi][ni][r]);
                }
            }
        }
    }
}

// out-projection: 64x64 tiles -> 512 blocks (2/CU, full machine), BK=64
// (8 barrier-drains).  acc + bias + residual fused, f32 store.  XCD m-grouping.
__global__ __launch_bounds__(256) void gemm_out(
        const bf16* __restrict__ o, const bf16* __restrict__ Wo_t,
        const float* __restrict__ bo, const float* __restrict__ x,
        float* __restrict__ out) {
    __shared__ __align__(16) unsigned short A_s[256][32];   // 2 bufs x 2 kc x 64 rows
    __shared__ __align__(16) unsigned short B_s[256][32];
    const int gid = blockIdx.x;                     // 0..511
    const int xcd = gid & 7, s = gid >> 3;          // s: 0..63
    const int n0 = (s & 7) * 64;
    const int m0 = (xcd * 8 + (s >> 3)) * 64;       // 64 m-tiles of 64 rows
    const int t = threadIdx.x;
    const int w = t >> 6, lane = t & 63;
    const int quad = lane >> 4, n16 = lane & 15;
    const int wm = (w >> 1) * 32, wn = (w & 1) * 32;

    f32x4 acc[2][2];
#pragma unroll
    for (int a = 0; a < 2; ++a)
#pragma unroll
        for (int b = 0; b < 2; ++b) acc[a][b] = (f32x4){0.f, 0.f, 0.f, 0.f};

    const int ar = lane >> 2, ac8 = (lane & 3) * 8;
    auto stage = [&](int k0, int buf) {
        const int bo = buf * 128;
#pragma unroll
        for (int kc = 0; kc < 2; ++kc) {
            GLD_LDS16(o    + (size_t)(m0 + w * 16 + ar) * 512 + k0 + kc * 32 + ac8,
                      &A_s[bo + kc * 64 + w * 16][0]);
            GLD_LDS16(Wo_t + (size_t)(n0 + w * 16 + ar) * 512 + k0 + kc * 32 + ac8,
                      &B_s[bo + kc * 64 + w * 16][0]);
        }
    };
    stage(0, 0);
    int cur = 0;
    for (int k0 = 0; k0 < 512; k0 += 64) {
        __syncthreads();
        if (k0 + 64 < 512) stage(k0 + 64, cur ^ 1);
        const int bo = cur * 128;
#pragma unroll
        for (int kc = 0; kc < 2; ++kc) {
            short8 af[2], bfr[2];
#pragma unroll
            for (int i = 0; i < 2; ++i) {
                af[i]  = *(const short8*)&A_s[bo + kc * 64 + wm + i * 16 + n16][quad * 8];
                bfr[i] = *(const short8*)&B_s[bo + kc * 64 + wn + i * 16 + n16][quad * 8];
            }
#pragma unroll
            for (int mi = 0; mi < 2; ++mi)
#pragma unroll
                for (int ni = 0; ni < 2; ++ni)
                    acc[mi][ni] = MFMA16(af[mi], bfr[ni], acc[mi][ni]);
        }
        cur ^= 1;
    }
#pragma unroll
    for (int mi = 0; mi < 2; ++mi) {
#pragma unroll
        for (int r = 0; r < 4; ++r) {
            int row = m0 + wm + mi * 16 + quad * 4 + r;
#pragma unroll
            for (int ni = 0; ni < 2; ++ni) {
                int col = n0 + wn + ni * 16 + n16;
                out[(size_t)row * 512 + col] =
                    acc[mi][ni][r] + bo[col] + x[(size_t)row * 512 + col];
            }
        }
    }
}

// ============ Fused MFMA flash attention, v8 (stable since R8) =============
// Pipeline QK_t || SM/PV_{t-1}, one barrier/tile, gl_lds K/P staging,
// setprio, O^T operand-swap PV, packed 8B epilogue.  Pinned at ~43 us across
// six structural variants (latency-chain-bound at 2 blocks/CU); R9 proved
// coalesced gl_lds P staging is load-bearing.
__global__ __launch_bounds__(256, 2) void attn_mfma_kernel(
        const bf16* __restrict__ q, const bf16* __restrict__ k,
        const bf16* __restrict__ v, const bf16* __restrict__ p,
        const float* __restrict__ cbias, const float* __restrict__ pbias,
        bf16* __restrict__ o) {
    __shared__ __align__(16) unsigned short k_s[2][4096];     // 64 rows x 64
    __shared__ __align__(16) unsigned short pw_s[2][8192];    // 128 rows x 64
    __shared__ __align__(16) unsigned short vt_s[2][64][72];  // V^T [d][j], padded
    __shared__ __align__(16) unsigned short gbuf[4][16][72];  // P tile per wave
    __shared__ float cb_s[64], pb_s[64];
    __shared__ float wrap_s;

    const int i0 = blockIdx.x * 64;
    const int h  = blockIdx.y;
    const int b  = blockIdx.z;
    const int t  = threadIdx.x;
    const int w    = t >> 6;
    const int lane = t & 63;
    const int quad = lane >> 4;
    const int n16  = lane & 15;
    const int h64  = h * 64;
    const float sc_scale = 0.125f * 1.4426950408889634f;   // (1/8)*log2(e)

    if (t < 64)       cb_s[t]      = cbias[h64 + t];
    else if (t < 128) pb_s[t - 64] = pbias[h64 + t - 64];

    // ---- per-lane staging sources (inverse-swizzled global addresses) ----
    const int l8 = lane >> 3, l7 = lane & 7;
    const int clog8 = (l7 ^ l8) * 8;          // logical chunk for this lane's LDS slot
    const unsigned short* ksrc[2];
    const unsigned short* psrc[4];
#pragma unroll
    for (int ps = 0; ps < 2; ++ps) {
        int row = (w * 2 + ps) * 8 + l8;
        ksrc[ps] = (const unsigned short*)k + ((size_t)(b * T_ + row) * 512 + h64 + clog8);
    }
    const int slb = T_ - i0 - 63;             // p row for pw_s row 0 at j0=0 (>=1)
#pragma unroll
    for (int ps = 0; ps < 4; ++ps) {
        int row = (w * 4 + ps) * 8 + l8;
        psrc[ps] = (const unsigned short*)p + ((size_t)(b * L_ + slb + row) * 512 + h64 + clog8);
    }
    auto stage = [&](int j0n, int nxt) {
        size_t joff = (size_t)j0n * 512;
#pragma unroll
        for (int ps = 0; ps < 2; ++ps)
            GLD_LDS16(ksrc[ps] + joff, &k_s[nxt][(w * 2 + ps) * 512]);
#pragma unroll
        for (int ps = 0; ps < 4; ++ps)
            GLD_LDS16(psrc[ps] + joff, &pw_s[nxt][(w * 4 + ps) * 512]);
    };

    // ---- V: reg-staged transpose (needs scatter, so no global_load_lds) ----
    const int vd2 = (t & 31) * 2, vjg = t >> 5;
    const unsigned short* vsrc = (const unsigned short*)v +
        ((size_t)(b * T_ + vjg * 8) * 512 + h64 + vd2);
    unsigned int vReg[8];
    auto vload = [&](int j0n) {
        const unsigned short* vg = vsrc + (size_t)j0n * 512;
#pragma unroll
        for (int e = 0; e < 8; ++e) vReg[e] = *(const unsigned int*)(vg + (size_t)e * 512);
    };
    auto vwrite = [&](int nxt) {
        uint4 wlo, whi;
        wlo.x = (vReg[0] & 0xffffu) | (vReg[1] << 16);
        wlo.y = (vReg[2] & 0xffffu) | (vReg[3] << 16);
        wlo.z = (vReg[4] & 0xffffu) | (vReg[5] << 16);
        wlo.w = (vReg[6] & 0xffffu) | (vReg[7] << 16);
        whi.x = (vReg[0] >> 16) | (vReg[1] & 0xffff0000u);
        whi.y = (vReg[2] >> 16) | (vReg[3] & 0xffff0000u);
        whi.z = (vReg[4] >> 16) | (vReg[5] & 0xffff0000u);
        whi.w = (vReg[6] >> 16) | (vReg[7] & 0xffff0000u);
        *(uint4*)&vt_s[nxt][vd2][vjg * 8]     = wlo;
        *(uint4*)&vt_s[nxt][vd2 + 1][vjg * 8] = whi;
    };

    stage(0, 0);
    vload(0);
    __syncthreads();   // stage(0)+vload(0) drained; cb_s/pb_s visible

    // ---- hoisted q-fragments, pre-scaled: ac=(q+cb)*s, ap=(q+pb)*s ----
    short8 ac[2], ap[2];
    {
        const unsigned short* qrow = (const unsigned short*)q +
            ((size_t)(b * T_ + i0 + 16 * w + n16) * 512 + h64);
#pragma unroll
        for (int kc = 0; kc < 2; ++kc) {
            uint4 u = *(const uint4*)(qrow + kc * 32 + quad * 8);
            const unsigned short* uv = (const unsigned short*)&u;
            unsigned short* acp = (unsigned short*)&ac[kc];
            unsigned short* app = (unsigned short*)&ap[kc];
#pragma unroll
            for (int e = 0; e < 8; ++e) {
                int d = kc * 32 + quad * 8 + e;
                float qv = bits2f(uv[e]);
                acp[e] = fbits((qv + cb_s[d]) * sc_scale);
                app[e] = fbits((qv + pb_s[d]) * sc_scale);
            }
        }
    }
    if (i0 == 0 && t < 64) {   // wrap positional: (q_1 + pb)·p_0 (pre-scaled)
        float part = (b2f(q[(size_t)(b * T_ + 1) * 512 + h64 + t]) + pb_s[t]) *
                     b2f(p[(size_t)(b * L_) * 512 + h64 + t]);
#pragma unroll
        for (int m = 1; m < 64; m <<= 1) part += __shfl_xor(part, m, 64);
        if (t == 0) wrap_s = part * sc_scale;
    }

    // ---- loop-invariant rel-shift gather constants ----
    int srcl[4]; bool hi_[4];
#pragma unroll
    for (int r = 0; r < 4; ++r) {
        int ii = quad * 4 + r;
        srcl[r] = (lane & 48) | ((n16 - ii - 1) & 15);
        hi_[r]  = n16 > ii;
    }
    short8 onesb;   // ones-ROW A fragment: row 0 = 1 -> C[0][i] = col-sums of B
    {
        const short ov = (n16 == 0) ? (short)0x3F80 : (short)0;
#pragma unroll
        for (int e = 0; e < 8; ++e) onesb[e] = ov;
    }

    const int pwoff = 48 - 16 * w;
    const int swzA  = (quad ^ (n16 & 7)) * 16;   // kc=0 swizzled chunk byte off
    const int swzB  = swzA ^ 64;                 // kc=1

    f32x4 O[4], O4;   // O[nt] = O^T quadrant: lane holds O[i=n16][d=nt*16+quad*4+r]
#pragma unroll
    for (int nt = 0; nt < 4; ++nt) O[nt] = (f32x4){0.f, 0.f, 0.f, 0.f};
    O4 = (f32x4){0.f, 0.f, 0.f, 0.f};

    // ---- QK: content (ac·K) + positional window (ap·P) for LDS buf ----
    auto qk = [&](f32x4 (&Sc)[4], f32x4 (&G)[5], int buf) {
        const char* krA  = (const char*)&k_s[buf][0]  + n16 * 128 + swzA;
        const char* krB  = (const char*)&k_s[buf][0]  + n16 * 128 + swzB;
        const char* pwrA = (const char*)&pw_s[buf][0] + (pwoff + n16) * 128 + swzA;
        const char* pwrB = (const char*)&pw_s[buf][0] + (pwoff + n16) * 128 + swzB;
#pragma unroll
        for (int nt = 0; nt < 4; ++nt) Sc[nt] = (f32x4){0.f, 0.f, 0.f, 0.f};
#pragma unroll
        for (int ct = 0; ct < 5; ++ct) G[ct] = (f32x4){0.f, 0.f, 0.f, 0.f};
        __builtin_amdgcn_s_setprio(1);
#pragma unroll
        for (int kc = 0; kc < 2; ++kc) {
#pragma unroll
            for (int nt = 0; nt < 4; ++nt) {
                short8 bk = *(const short8*)((kc ? krB : krA) + nt * 2048);
                Sc[nt] = MFMA16(ac[kc], bk, Sc[nt]);
            }
#pragma unroll
            for (int ct = 0; ct < 5; ++ct) {
                short8 bp = *(const short8*)((kc ? pwrB : pwrA) + ct * 2048);
                G[ct] = MFMA16(ap[kc], bp, G[ct]);
            }
        }
        __builtin_amdgcn_s_setprio(0);
    };

    // ---- softmax (rel-shift gather + exp2) + transposed PV ----
    auto sm_pv = [&](const f32x4 (&Sc)[4], const f32x4 (&G)[5], int vb, bool dowrap) {
        short8 vbr[2][4];
#pragma unroll
        for (int kc = 0; kc < 2; ++kc)
#pragma unroll
            for (int nt = 0; nt < 4; ++nt)
                vbr[kc][nt] = *(const short8*)&vt_s[vb][nt * 16 + n16][kc * 32 + quad * 8];
        float pe[4][4];
#pragma unroll
        for (int r = 0; r < 4; ++r) {
            float s0 = __shfl(G[0][r], srcl[r], 64);
            float s1 = __shfl(G[1][r], srcl[r], 64);
            float s2 = __shfl(G[2][r], srcl[r], 64);
            float s3 = __shfl(G[3][r], srcl[r], 64);
            float s4 = __shfl(G[4][r], srcl[r], 64);
            pe[0][r] = Sc[0][r] + (hi_[r] ? s1 : s0);
            pe[1][r] = Sc[1][r] + (hi_[r] ? s2 : s1);
            pe[2][r] = Sc[2][r] + (hi_[r] ? s3 : s2);
            pe[3][r] = Sc[3][r] + (hi_[r] ? s4 : s3);
        }
        if (dowrap && i0 == 0 && w == 0 && lane == 15)   // wrap (i=0, j=T-1)
            pe[3][0] = Sc[3][0] + wrap_s;
#pragma unroll
        for (int ct = 0; ct < 4; ++ct)
#pragma unroll
            for (int r = 0; r < 4; ++r)
                *(bf16*)&gbuf[w][quad * 4 + r][ct * 16 + n16] = f2b(exp2f(pe[ct][r]));
        __builtin_amdgcn_s_setprio(1);
#pragma unroll
        for (int kc = 0; kc < 2; ++kc) {
            short8 pa = *(const short8*)&gbuf[w][n16][kc * 32 + quad * 8];
#pragma unroll
            for (int nt = 0; nt < 4; ++nt)
                O[nt] = MFMA16(vbr[kc][nt], pa, O[nt]);   // C[d][i] = O^T
            O4 = MFMA16(onesb, pa, O4);                   // C[0][i] = l[i]
        }
        __builtin_amdgcn_s_setprio(0);
    };

    f32x4 ScA[4], GA[5], ScB[4], GB[5];

    // ---- prologue: tile 0 staged; write V0, prefetch tile 1, compute QK_0 ----
    stage(64, 1);
    vwrite(0);                 // vt buf0 <- V tile 0 (published by next barrier)
    vload(64);
    qk(ScA, GA, 0);

    // ---- pipelined body: iteration tt does QK_tt and SM/PV_{tt-1} ----
    auto body = [&](int tt, f32x4 (&ScC)[4], f32x4 (&GC)[5],
                    const f32x4 (&ScP)[4], const f32x4 (&GP)[5], bool more) {
        __syncthreads();       // stage(tt)+vload(tt) drained; vwrite(tt-1) visible
        if (more) stage((tt + 1) * 64, (tt + 1) & 1);
        vwrite(tt & 1);        // vt buf[tt&1] <- V tile tt (vReg from prev iter)
        if (more) vload((tt + 1) * 64);
        qk(ScC, GC, tt & 1);           // independent MFMA stream
        sm_pv(ScP, GP, (tt - 1) & 1, false);   // register chain from prev tile
    };

#pragma unroll
    for (int tp = 0; tp < 7; ++tp) {
        body(2 * tp + 1, ScB, GB, ScA, GA, true);
        body(2 * tp + 2, ScA, GA, ScB, GB, true);
    }
    body(15, ScB, GB, ScA, GA, false);

    // ---- drain: SM/PV for tile 15 (needs other waves' vwrite(15)) ----
    __syncthreads();
    sm_pv(ScB, GB, 1, true);

    // ---- epilogue: l[i] lives in lane i's O4[0] (quad 0 row); O^T is
    // lane-local in d -> packed 8B stores of 4 consecutive d per nt ----
    {
        float inv = 1.f / __shfl(O4[0], lane & 15, 64);
        unsigned short* orow = (unsigned short*)o +
            ((size_t)(b * T_ + i0 + 16 * w + n16) * 512 + h64);
#pragma unroll
        for (int nt = 0; nt < 4; ++nt) {
            uint2 pk;
            pk.x = (unsigned)fbits(O[nt][0] * inv) | ((unsigned)fbits(O[nt][1] * inv) << 16);
            pk.y = (unsigned)fbits(O[nt][2] * inv) | ((unsigned)fbits(O[nt][3] * inv) << 16);
            *(uint2*)(orow + nt * 16 + quad * 4) = pk;
        }
    }
}

extern "C" void kernel_launch(void* const* d_in, const int* in_sizes, int n_in,
                              void* d_out, int out_size, void* d_ws, size_t ws_size,
                              hipStream_t stream) {
    (void)in_sizes; (void)n_in; (void)out_size;
    const float* x     = (const float*)d_in[0];
    const float* pos   = (const float*)d_in[1];
    const float* cb    = (const float*)d_in[2];
    const float* pb    = (const float*)d_in[3];
    const float* gamma = (const float*)d_in[4];
    const float* beta  = (const float*)d_in[5];
    const float* Wq    = (const float*)d_in[6];
    const float* bq    = (const float*)d_in[7];
    const float* Wk    = (const float*)d_in[8];
    const float* bk    = (const float*)d_in[9];
    const float* Wv    = (const float*)d_in[10];
    const float* bv    = (const float*)d_in[11];
    const float* Wp    = (const float*)d_in[12];
    const float* Wo    = (const float*)d_in[13];
    const float* bo    = (const float*)d_in[14];
    float* out = (float*)d_out;

    const int BT = B_ * T_;       // 4096

    const size_t sz_bt = (size_t)BT * D_;            // 2,097,152
    const size_t sz_bl = (size_t)(B_ * L_) * D_;     // 4,192,256
    const size_t sz_w  = 512 * 512;
    const size_t need  = (5 * sz_bt + sz_bl + 5 * sz_w) * sizeof(bf16) + 1536 * sizeof(float);
    if (ws_size < need) return;

    // ws layout: y | o | q | k | v | p | Wqkv_t | Wp_t | Wo_t | biasq
    bf16* y       = (bf16*)d_ws;
    bf16* o       = y + sz_bt;
    bf16* q       = y + 2 * sz_bt;
    bf16* k       = y + 3 * sz_bt;
    bf16* v       = y + 4 * sz_bt;
    bf16* p       = y + 5 * sz_bt;
    bf16* Wqkv_t  = p + sz_bl;
    bf16* Wp_t    = Wqkv_t + 3 * sz_w;
    bf16* Wo_t    = Wp_t + sz_w;
    float* biasq  = (float*)(Wo_t + sz_w);
    // pos_bf scratch lives in d_out (8,388,608 B f32 region; pos_bf needs
    // 8188*512*2 = 8,384,512 B; p-GEMM OOB A-tile rows stay within the 8 MB).
    // gemm_out later overwrites every element of d_out.
    bf16* pos_bf  = (bf16*)d_out;

    prep_all<<<7429, 256, 0, stream>>>(Wq, Wk, Wv, Wp, Wo, bq, bk, bv, pos, x,
                                       gamma, beta, Wqkv_t, Wp_t, Wo_t, biasq, pos_bf, y);

    // qkv: 768 x 64x128 tiles + p: 512 x 64x128 tiles = 1280 uniform jobs, BK=32
    gemm_qkvp<<<1280, 256, 0, stream>>>(y, pos_bf, Wqkv_t, Wp_t, biasq, q, p, sz_bt);

    attn_mfma_kernel<<<dim3(T_ / 64, H_, B_), 256, 0, stream>>>(q, k, v, p, cb, pb, o);

    // out: [4096,512]x[512,512] + bo + x residual -> f32 d_out, 512 x 64x64 tiles
    gemm_out<<<512, 256, 0, stream>>>(o, Wo_t, bo, x, out);
}

// Round 12
// 170.757 us; speedup vs baseline: 1.1456x; 1.0141x over previous
//
#include <hip/hip_runtime.h>
#include <hip/hip_bf16.h>

typedef __hip_bfloat16 bf16;
typedef __attribute__((ext_vector_type(8))) short short8;
typedef __attribute__((ext_vector_type(4))) float f32x4;

#define B_  4
#define T_  1024
#define D_  512
#define H_  8
#define DK_ 64
#define L_  2047   // 2*T - 1

__device__ __forceinline__ float b2f(bf16 v) { return __bfloat162float(v); }
__device__ __forceinline__ bf16  f2b(float v) { return __float2bfloat16(v); }
__device__ __forceinline__ float bits2f(unsigned short u) {
    return __uint_as_float(((unsigned int)u) << 16);
}
__device__ __forceinline__ unsigned short fbits(float v) {
    bf16 h = f2b(v); return *(unsigned short*)&h;
}

#define MFMA16(a, b, c) __builtin_amdgcn_mfma_f32_16x16x32_bf16(a, b, c, 0, 0, 0)
#define GLD_LDS16(g, l) __builtin_amdgcn_global_load_lds( \
    (const __attribute__((address_space(1))) unsigned int*)(g), \
    (__attribute__((address_space(3))) unsigned int*)(l), 16, 0, 0)

// ============ prep_all: weight transpose + bias concat + pos cvt + layernorm ============
// flat grid: [0,1280) weights, [1280,1286) bias, [1286,3333) pos_cvt, [3333,7429) lnorm
__global__ __launch_bounds__(256) void prep_all(
        const float* __restrict__ Wq, const float* __restrict__ Wk,
        const float* __restrict__ Wv, const float* __restrict__ Wp,
        const float* __restrict__ Wo,
        const float* __restrict__ bq, const float* __restrict__ bk,
        const float* __restrict__ bv,
        const float* __restrict__ pos, const float* __restrict__ x,
        const float* __restrict__ gamma, const float* __restrict__ beta,
        bf16* __restrict__ Wqkv_t, bf16* __restrict__ Wp_t, bf16* __restrict__ Wo_t,
        float* __restrict__ biasq, bf16* __restrict__ pos_bf, bf16* __restrict__ y) {
    __shared__ float tl[32][33];
    __shared__ float ws1[4], ws2[4];
    const int blk = blockIdx.x;
    const int t = threadIdx.x;

    if (blk < 1280) {            // ---- weight transpose: f32 [k][n] -> bf16 [n][k] ----
        const int z = blk >> 8, rem = blk & 255;
        const float* W; bf16* Wt; int roff;
        switch (z) {
            case 0: W = Wq; Wt = Wqkv_t; roff = 0;    break;
            case 1: W = Wk; Wt = Wqkv_t; roff = 512;  break;
            case 2: W = Wv; Wt = Wqkv_t; roff = 1024; break;
            case 3: W = Wp; Wt = Wp_t;   roff = 0;    break;
            default: W = Wo; Wt = Wo_t;  roff = 0;    break;
        }
        const int n0 = (rem & 15) * 32, k0 = (rem >> 4) * 32;
        const int tx = t & 31, ty = t >> 5;
#pragma unroll
        for (int r = 0; r < 4; ++r)
            tl[ty + r * 8][tx] = W[(size_t)(k0 + ty + r * 8) * 512 + n0 + tx];
        __syncthreads();
#pragma unroll
        for (int r = 0; r < 4; ++r)
            Wt[(size_t)(roff + n0 + ty + r * 8) * 512 + k0 + tx] = f2b(tl[tx][ty + r * 8]);
    } else if (blk < 1286) {     // ---- bias concat ----
        int i = (blk - 1280) * 256 + t;
        biasq[i] = (i < 512) ? bq[i] : (i < 1024) ? bk[i - 512] : bv[i - 1024];
    } else if (blk < 3333) {     // ---- pos f32 -> bf16 ----
        size_t i = ((size_t)(blk - 1286) * 256 + t) * 8;
        float4 a = *(const float4*)(pos + i);
        float4 c = *(const float4*)(pos + i + 4);
        uint4 wv;
        wv.x = ((unsigned)fbits(a.y) << 16) | fbits(a.x);
        wv.y = ((unsigned)fbits(a.w) << 16) | fbits(a.z);
        wv.z = ((unsigned)fbits(c.y) << 16) | fbits(c.x);
        wv.w = ((unsigned)fbits(c.w) << 16) | fbits(c.z);
        *(uint4*)((unsigned short*)pos_bf + i) = wv;
    } else {                     // ---- layernorm row ----
        const int row = blk - 3333;
        const float* xr = x + (size_t)row * D_;
        float v0 = xr[t];
        float v1 = xr[t + 256];
        float s  = v0 + v1;
        float s2 = v0 * v0 + v1 * v1;
#pragma unroll
        for (int off = 32; off > 0; off >>= 1) {
            s  += __shfl_down(s,  off, 64);
            s2 += __shfl_down(s2, off, 64);
        }
        const int wid = t >> 6, lane = t & 63;
        if (!lane) { ws1[wid] = s; ws2[wid] = s2; }
        __syncthreads();
        float S  = ws1[0] + ws1[1] + ws1[2] + ws1[3];
        float S2 = ws2[0] + ws2[1] + ws2[2] + ws2[3];
        float mean = S * (1.f / D_);
        float var  = S2 * (1.f / D_) - mean * mean;
        float r = rsqrtf(var + 1e-3f);
        bf16* yr = y + (size_t)row * D_;
        yr[t]       = f2b((v0 - mean) * r * gamma[t]       + beta[t]);
        yr[t + 256] = f2b((v1 - mean) * r * gamma[t + 256] + beta[t + 256]);
    }
}

// qkv GEMM (384 blocks) + p GEMM (256 blocks), ALL uniform 128x128 BK=32.
// 640 jobs <= 1024 resident at launch_bounds(256,4) -> SINGLE occupancy round
// with 16 MFMAs per barrier-drain (R11's 64x128 had only 8/drain and 1.25
// rounds).  ~115 VGPR fits 4 waves/SIMD.  Ascending K-order unchanged ->
// bitwise-identical q/k/v/p.  XCD-aware decode keeps A-panel L2 reuse.
__global__ __launch_bounds__(256, 4) void gemm_qkvp(
        const bf16* __restrict__ y, const bf16* __restrict__ pos_bf,
        const bf16* __restrict__ Wqkv_t, const bf16* __restrict__ Wp_t,
        const float* __restrict__ biasq,
        bf16* __restrict__ q, bf16* __restrict__ p, size_t seg_elems) {
    __shared__ __align__(16) unsigned short A_s[256][32];   // 2 bufs x 128 rows
    __shared__ __align__(16) unsigned short B_s[256][32];
    const int gid = blockIdx.x;
    const int t = threadIdx.x;
    const int w = t >> 6, lane = t & 63;
    const int quad = lane >> 4, n16 = lane & 15;
    const int ar = lane >> 2, ac8 = (lane & 3) * 8;
    const int wm = (w >> 1) * 64, wn = (w & 1) * 64;

    const bf16* A; const bf16* Bw; int m0, n0; bool isqkv;
    if (gid < 384) {
        // ---- qkv: [4096,512] x [512,1536] ----
        const int xcd = gid & 7, s = gid >> 3;       // s: 0..47
        n0 = (s % 12) * 128;
        m0 = (xcd * 4 + s / 12) * 128;               // 32 m-tiles of 128 rows
        A = y; Bw = Wqkv_t; isqkv = true;
    } else {
        // ---- p: [8188,512] x [512,512] ----
        const int g2 = gid - 384;                    // 0..255 (384%8==0)
        const int xcd = g2 & 7, s = g2 >> 3;         // s: 0..31
        n0 = (s & 3) * 128;
        m0 = (xcd * 8 + (s >> 2)) * 128;             // 64 m-tiles of 128 rows
        A = pos_bf; Bw = Wp_t; isqkv = false;
        // A loads for rows up to 8191 stay inside pos_bf's 8 MB d_out region
        // (8192*1024B == d_out size); stores are M-guarded.
    }

    f32x4 acc[4][4];
#pragma unroll
    for (int a = 0; a < 4; ++a)
#pragma unroll
        for (int b = 0; b < 4; ++b) acc[a][b] = (f32x4){0.f, 0.f, 0.f, 0.f};

    auto stage = [&](int k0, int buf) {
        const int bo = buf << 7;
#pragma unroll
        for (int ps = 0; ps < 2; ++ps) {
            int br = (ps * 4 + w) * 16;
            GLD_LDS16(A  + (size_t)(m0 + br + ar) * 512 + k0 + ac8, &A_s[bo + br][0]);
            GLD_LDS16(Bw + (size_t)(n0 + br + ar) * 512 + k0 + ac8, &B_s[bo + br][0]);
        }
    };
    stage(0, 0);
    int cur = 0;
    for (int k0 = 0; k0 < 512; k0 += 32) {
        __syncthreads();
        if (k0 + 32 < 512) stage(k0 + 32, cur ^ 1);
        const int bo = cur << 7;
        short8 af[4], bfr[4];
#pragma unroll
        for (int i = 0; i < 4; ++i) {
            af[i]  = *(const short8*)&A_s[bo + wm + i * 16 + n16][quad * 8];
            bfr[i] = *(const short8*)&B_s[bo + wn + i * 16 + n16][quad * 8];
        }
#pragma unroll
        for (int mi = 0; mi < 4; ++mi)
#pragma unroll
            for (int ni = 0; ni < 4; ++ni)
                acc[mi][ni] = MFMA16(af[mi], bfr[ni], acc[mi][ni]);
        cur ^= 1;
    }

    if (isqkv) {
#pragma unroll
        for (int mi = 0; mi < 4; ++mi) {
#pragma unroll
            for (int r = 0; r < 4; ++r) {
                int row = m0 + wm + mi * 16 + quad * 4 + r;
#pragma unroll
                for (int ni = 0; ni < 4; ++ni) {
                    int col  = n0 + wn + ni * 16 + n16;
                    int coll = col & 511;
                    bf16* Cp = q + (size_t)(col >> 9) * seg_elems;
                    Cp[(size_t)row * 512 + coll] = f2b(acc[mi][ni][r] + biasq[col]);
                }
            }
        }
    } else {
#pragma unroll
        for (int mi = 0; mi < 4; ++mi) {
#pragma unroll
            for (int r = 0; r < 4; ++r) {
                int row = m0 + wm + mi * 16 + quad * 4 + r;
                if (row >= 8188) continue;
#pragma unroll
                for (int ni = 0; ni < 4; ++ni) {
                    int col = n0 + wn + ni * 16 + n16;
                    p[(size_t)row * 512 + col] = f2b(acc[mi][ni][r]);
                }
            }
        }
    }
}

// out-projection: 64x64 tiles -> 512 blocks (2/CU, full machine), BK=64
// (8 barrier-drains).  acc + bias + residual fused, f32 store.  XCD m-grouping.
__global__ __launch_bounds__(256) void gemm_out(
        const bf16* __restrict__ o, const bf16* __restrict__ Wo_t,
        const float* __restrict__ bo, const float* __restrict__ x,
        float* __restrict__ out) {
    __shared__ __align__(16) unsigned short A_s[256][32];   // 2 bufs x 2 kc x 64 rows
    __shared__ __align__(16) unsigned short B_s[256][32];
    const int gid = blockIdx.x;                     // 0..511
    const int xcd = gid & 7, s = gid >> 3;          // s: 0..63
    const int n0 = (s & 7) * 64;
    const int m0 = (xcd * 8 + (s >> 3)) * 64;       // 64 m-tiles of 64 rows
    const int t = threadIdx.x;
    const int w = t >> 6, lane = t & 63;
    const int quad = lane >> 4, n16 = lane & 15;
    const int wm = (w >> 1) * 32, wn = (w & 1) * 32;

    f32x4 acc[2][2];
#pragma unroll
    for (int a = 0; a < 2; ++a)
#pragma unroll
        for (int b = 0; b < 2; ++b) acc[a][b] = (f32x4){0.f, 0.f, 0.f, 0.f};

    const int ar = lane >> 2, ac8 = (lane & 3) * 8;
    auto stage = [&](int k0, int buf) {
        const int bo = buf * 128;
#pragma unroll
        for (int kc = 0; kc < 2; ++kc) {
            GLD_LDS16(o    + (size_t)(m0 + w * 16 + ar) * 512 + k0 + kc * 32 + ac8,
                      &A_s[bo + kc * 64 + w * 16][0]);
            GLD_LDS16(Wo_t + (size_t)(n0 + w * 16 + ar) * 512 + k0 + kc * 32 + ac8,
                      &B_s[bo + kc * 64 + w * 16][0]);
        }
    };
    stage(0, 0);
    int cur = 0;
    for (int k0 = 0; k0 < 512; k0 += 64) {
        __syncthreads();
        if (k0 + 64 < 512) stage(k0 + 64, cur ^ 1);
        const int bo = cur * 128;
#pragma unroll
        for (int kc = 0; kc < 2; ++kc) {
            short8 af[2], bfr[2];
#pragma unroll
            for (int i = 0; i < 2; ++i) {
                af[i]  = *(const short8*)&A_s[bo + kc * 64 + wm + i * 16 + n16][quad * 8];
                bfr[i] = *(const short8*)&B_s[bo + kc * 64 + wn + i * 16 + n16][quad * 8];
            }
#pragma unroll
            for (int mi = 0; mi < 2; ++mi)
#pragma unroll
                for (int ni = 0; ni < 2; ++ni)
                    acc[mi][ni] = MFMA16(af[mi], bfr[ni], acc[mi][ni]);
        }
        cur ^= 1;
    }
#pragma unroll
    for (int mi = 0; mi < 2; ++mi) {
#pragma unroll
        for (int r = 0; r < 4; ++r) {
            int row = m0 + wm + mi * 16 + quad * 4 + r;
#pragma unroll
            for (int ni = 0; ni < 2; ++ni) {
                int col = n0 + wn + ni * 16 + n16;
                out[(size_t)row * 512 + col] =
                    acc[mi][ni][r] + bo[col] + x[(size_t)row * 512 + col];
            }
        }
    }
}

// ============ Fused MFMA flash attention, v8 (stable since R8) =============
// Pipeline QK_t || SM/PV_{t-1}, one barrier/tile, gl_lds K/P staging,
// setprio, O^T operand-swap PV, packed 8B epilogue.  Pinned at ~43 us across
// six structural variants (latency-chain-bound at 2 blocks/CU); R9 proved
// coalesced gl_lds P staging is load-bearing.
__global__ __launch_bounds__(256, 2) void attn_mfma_kernel(
        const bf16* __restrict__ q, const bf16* __restrict__ k,
        const bf16* __restrict__ v, const bf16* __restrict__ p,
        const float* __restrict__ cbias, const float* __restrict__ pbias,
        bf16* __restrict__ o) {
    __shared__ __align__(16) unsigned short k_s[2][4096];     // 64 rows x 64
    __shared__ __align__(16) unsigned short pw_s[2][8192];    // 128 rows x 64
    __shared__ __align__(16) unsigned short vt_s[2][64][72];  // V^T [d][j], padded
    __shared__ __align__(16) unsigned short gbuf[4][16][72];  // P tile per wave
    __shared__ float cb_s[64], pb_s[64];
    __shared__ float wrap_s;

    const int i0 = blockIdx.x * 64;
    const int h  = blockIdx.y;
    const int b  = blockIdx.z;
    const int t  = threadIdx.x;
    const int w    = t >> 6;
    const int lane = t & 63;
    const int quad = lane >> 4;
    const int n16  = lane & 15;
    const int h64  = h * 64;
    const float sc_scale = 0.125f * 1.4426950408889634f;   // (1/8)*log2(e)

    if (t < 64)       cb_s[t]      = cbias[h64 + t];
    else if (t < 128) pb_s[t - 64] = pbias[h64 + t - 64];

    // ---- per-lane staging sources (inverse-swizzled global addresses) ----
    const int l8 = lane >> 3, l7 = lane & 7;
    const int clog8 = (l7 ^ l8) * 8;          // logical chunk for this lane's LDS slot
    const unsigned short* ksrc[2];
    const unsigned short* psrc[4];
#pragma unroll
    for (int ps = 0; ps < 2; ++ps) {
        int row = (w * 2 + ps) * 8 + l8;
        ksrc[ps] = (const unsigned short*)k + ((size_t)(b * T_ + row) * 512 + h64 + clog8);
    }
    const int slb = T_ - i0 - 63;             // p row for pw_s row 0 at j0=0 (>=1)
#pragma unroll
    for (int ps = 0; ps < 4; ++ps) {
        int row = (w * 4 + ps) * 8 + l8;
        psrc[ps] = (const unsigned short*)p + ((size_t)(b * L_ + slb + row) * 512 + h64 + clog8);
    }
    auto stage = [&](int j0n, int nxt) {
        size_t joff = (size_t)j0n * 512;
#pragma unroll
        for (int ps = 0; ps < 2; ++ps)
            GLD_LDS16(ksrc[ps] + joff, &k_s[nxt][(w * 2 + ps) * 512]);
#pragma unroll
        for (int ps = 0; ps < 4; ++ps)
            GLD_LDS16(psrc[ps] + joff, &pw_s[nxt][(w * 4 + ps) * 512]);
    };

    // ---- V: reg-staged transpose (needs scatter, so no global_load_lds) ----
    const int vd2 = (t & 31) * 2, vjg = t >> 5;
    const unsigned short* vsrc = (const unsigned short*)v +
        ((size_t)(b * T_ + vjg * 8) * 512 + h64 + vd2);
    unsigned int vReg[8];
    auto vload = [&](int j0n) {
        const unsigned short* vg = vsrc + (size_t)j0n * 512;
#pragma unroll
        for (int e = 0; e < 8; ++e) vReg[e] = *(const unsigned int*)(vg + (size_t)e * 512);
    };
    auto vwrite = [&](int nxt) {
        uint4 wlo, whi;
        wlo.x = (vReg[0] & 0xffffu) | (vReg[1] << 16);
        wlo.y = (vReg[2] & 0xffffu) | (vReg[3] << 16);
        wlo.z = (vReg[4] & 0xffffu) | (vReg[5] << 16);
        wlo.w = (vReg[6] & 0xffffu) | (vReg[7] << 16);
        whi.x = (vReg[0] >> 16) | (vReg[1] & 0xffff0000u);
        whi.y = (vReg[2] >> 16) | (vReg[3] & 0xffff0000u);
        whi.z = (vReg[4] >> 16) | (vReg[5] & 0xffff0000u);
        whi.w = (vReg[6] >> 16) | (vReg[7] & 0xffff0000u);
        *(uint4*)&vt_s[nxt][vd2][vjg * 8]     = wlo;
        *(uint4*)&vt_s[nxt][vd2 + 1][vjg * 8] = whi;
    };

    stage(0, 0);
    vload(0);
    __syncthreads();   // stage(0)+vload(0) drained; cb_s/pb_s visible

    // ---- hoisted q-fragments, pre-scaled: ac=(q+cb)*s, ap=(q+pb)*s ----
    short8 ac[2], ap[2];
    {
        const unsigned short* qrow = (const unsigned short*)q +
            ((size_t)(b * T_ + i0 + 16 * w + n16) * 512 + h64);
#pragma unroll
        for (int kc = 0; kc < 2; ++kc) {
            uint4 u = *(const uint4*)(qrow + kc * 32 + quad * 8);
            const unsigned short* uv = (const unsigned short*)&u;
            unsigned short* acp = (unsigned short*)&ac[kc];
            unsigned short* app = (unsigned short*)&ap[kc];
#pragma unroll
            for (int e = 0; e < 8; ++e) {
                int d = kc * 32 + quad * 8 + e;
                float qv = bits2f(uv[e]);
                acp[e] = fbits((qv + cb_s[d]) * sc_scale);
                app[e] = fbits((qv + pb_s[d]) * sc_scale);
            }
        }
    }
    if (i0 == 0 && t < 64) {   // wrap positional: (q_1 + pb)·p_0 (pre-scaled)
        float part = (b2f(q[(size_t)(b * T_ + 1) * 512 + h64 + t]) + pb_s[t]) *
                     b2f(p[(size_t)(b * L_) * 512 + h64 + t]);
#pragma unroll
        for (int m = 1; m < 64; m <<= 1) part += __shfl_xor(part, m, 64);
        if (t == 0) wrap_s = part * sc_scale;
    }

    // ---- loop-invariant rel-shift gather constants ----
    int srcl[4]; bool hi_[4];
#pragma unroll
    for (int r = 0; r < 4; ++r) {
        int ii = quad * 4 + r;
        srcl[r] = (lane & 48) | ((n16 - ii - 1) & 15);
        hi_[r]  = n16 > ii;
    }
    short8 onesb;   // ones-ROW A fragment: row 0 = 1 -> C[0][i] = col-sums of B
    {
        const short ov = (n16 == 0) ? (short)0x3F80 : (short)0;
#pragma unroll
        for (int e = 0; e < 8; ++e) onesb[e] = ov;
    }

    const int pwoff = 48 - 16 * w;
    const int swzA  = (quad ^ (n16 & 7)) * 16;   // kc=0 swizzled chunk byte off
    const int swzB  = swzA ^ 64;                 // kc=1

    f32x4 O[4], O4;   // O[nt] = O^T quadrant: lane holds O[i=n16][d=nt*16+quad*4+r]
#pragma unroll
    for (int nt = 0; nt < 4; ++nt) O[nt] = (f32x4){0.f, 0.f, 0.f, 0.f};
    O4 = (f32x4){0.f, 0.f, 0.f, 0.f};

    // ---- QK: content (ac·K) + positional window (ap·P) for LDS buf ----
    auto qk = [&](f32x4 (&Sc)[4], f32x4 (&G)[5], int buf) {
        const char* krA  = (const char*)&k_s[buf][0]  + n16 * 128 + swzA;
        const char* krB  = (const char*)&k_s[buf][0]  + n16 * 128 + swzB;
        const char* pwrA = (const char*)&pw_s[buf][0] + (pwoff + n16) * 128 + swzA;
        const char* pwrB = (const char*)&pw_s[buf][0] + (pwoff + n16) * 128 + swzB;
#pragma unroll
        for (int nt = 0; nt < 4; ++nt) Sc[nt] = (f32x4){0.f, 0.f, 0.f, 0.f};
#pragma unroll
        for (int ct = 0; ct < 5; ++ct) G[ct] = (f32x4){0.f, 0.f, 0.f, 0.f};
        __builtin_amdgcn_s_setprio(1);
#pragma unroll
        for (int kc = 0; kc < 2; ++kc) {
#pragma unroll
            for (int nt = 0; nt < 4; ++nt) {
                short8 bk = *(const short8*)((kc ? krB : krA) + nt * 2048);
                Sc[nt] = MFMA16(ac[kc], bk, Sc[nt]);
            }
#pragma unroll
            for (int ct = 0; ct < 5; ++ct) {
                short8 bp = *(const short8*)((kc ? pwrB : pwrA) + ct * 2048);
                G[ct] = MFMA16(ap[kc], bp, G[ct]);
            }
        }
        __builtin_amdgcn_s_setprio(0);
    };

    // ---- softmax (rel-shift gather + exp2) + transposed PV ----
    auto sm_pv = [&](const f32x4 (&Sc)[4], const f32x4 (&G)[5], int vb, bool dowrap) {
        short8 vbr[2][4];
#pragma unroll
        for (int kc = 0; kc < 2; ++kc)
#pragma unroll
            for (int nt = 0; nt < 4; ++nt)
                vbr[kc][nt] = *(const short8*)&vt_s[vb][nt * 16 + n16][kc * 32 + quad * 8];
        float pe[4][4];
#pragma unroll
        for (int r = 0; r < 4; ++r) {
            float s0 = __shfl(G[0][r], srcl[r], 64);
            float s1 = __shfl(G[1][r], srcl[r], 64);
            float s2 = __shfl(G[2][r], srcl[r], 64);
            float s3 = __shfl(G[3][r], srcl[r], 64);
            float s4 = __shfl(G[4][r], srcl[r], 64);
            pe[0][r] = Sc[0][r] + (hi_[r] ? s1 : s0);
            pe[1][r] = Sc[1][r] + (hi_[r] ? s2 : s1);
            pe[2][r] = Sc[2][r] + (hi_[r] ? s3 : s2);
            pe[3][r] = Sc[3][r] + (hi_[r] ? s4 : s3);
        }
        if (dowrap && i0 == 0 && w == 0 && lane == 15)   // wrap (i=0, j=T-1)
            pe[3][0] = Sc[3][0] + wrap_s;
#pragma unroll
        for (int ct = 0; ct < 4; ++ct)
#pragma unroll
            for (int r = 0; r < 4; ++r)
                *(bf16*)&gbuf[w][quad * 4 + r][ct * 16 + n16] = f2b(exp2f(pe[ct][r]));
        __builtin_amdgcn_s_setprio(1);
#pragma unroll
        for (int kc = 0; kc < 2; ++kc) {
            short8 pa = *(const short8*)&gbuf[w][n16][kc * 32 + quad * 8];
#pragma unroll
            for (int nt = 0; nt < 4; ++nt)
                O[nt] = MFMA16(vbr[kc][nt], pa, O[nt]);   // C[d][i] = O^T
            O4 = MFMA16(onesb, pa, O4);                   // C[0][i] = l[i]
        }
        __builtin_amdgcn_s_setprio(0);
    };

    f32x4 ScA[4], GA[5], ScB[4], GB[5];

    // ---- prologue: tile 0 staged; write V0, prefetch tile 1, compute QK_0 ----
    stage(64, 1);
    vwrite(0);                 // vt buf0 <- V tile 0 (published by next barrier)
    vload(64);
    qk(ScA, GA, 0);

    // ---- pipelined body: iteration tt does QK_tt and SM/PV_{tt-1} ----
    auto body = [&](int tt, f32x4 (&ScC)[4], f32x4 (&GC)[5],
                    const f32x4 (&ScP)[4], const f32x4 (&GP)[5], bool more) {
        __syncthreads();       // stage(tt)+vload(tt) drained; vwrite(tt-1) visible
        if (more) stage((tt + 1) * 64, (tt + 1) & 1);
        vwrite(tt & 1);        // vt buf[tt&1] <- V tile tt (vReg from prev iter)
        if (more) vload((tt + 1) * 64);
        qk(ScC, GC, tt & 1);           // independent MFMA stream
        sm_pv(ScP, GP, (tt - 1) & 1, false);   // register chain from prev tile
    };

#pragma unroll
    for (int tp = 0; tp < 7; ++tp) {
        body(2 * tp + 1, ScB, GB, ScA, GA, true);
        body(2 * tp + 2, ScA, GA, ScB, GB, true);
    }
    body(15, ScB, GB, ScA, GA, false);

    // ---- drain: SM/PV for tile 15 (needs other waves' vwrite(15)) ----
    __syncthreads();
    sm_pv(ScB, GB, 1, true);

    // ---- epilogue: l[i] lives in lane i's O4[0] (quad 0 row); O^T is
    // lane-local in d -> packed 8B stores of 4 consecutive d per nt ----
    {
        float inv = 1.f / __shfl(O4[0], lane & 15, 64);
        unsigned short* orow = (unsigned short*)o +
            ((size_t)(b * T_ + i0 + 16 * w + n16) * 512 + h64);
#pragma unroll
        for (int nt = 0; nt < 4; ++nt) {
            uint2 pk;
            pk.x = (unsigned)fbits(O[nt][0] * inv) | ((unsigned)fbits(O[nt][1] * inv) << 16);
            pk.y = (unsigned)fbits(O[nt][2] * inv) | ((unsigned)fbits(O[nt][3] * inv) << 16);
            *(uint2*)(orow + nt * 16 + quad * 4) = pk;
        }
    }
}

extern "C" void kernel_launch(void* const* d_in, const int* in_sizes, int n_in,
                              void* d_out, int out_size, void* d_ws, size_t ws_size,
                              hipStream_t stream) {
    (void)in_sizes; (void)n_in; (void)out_size;
    const float* x     = (const float*)d_in[0];
    const float* pos   = (const float*)d_in[1];
    const float* cb    = (const float*)d_in[2];
    const float* pb    = (const float*)d_in[3];
    const float* gamma = (const float*)d_in[4];
    const float* beta  = (const float*)d_in[5];
    const float* Wq    = (const float*)d_in[6];
    const float* bq    = (const float*)d_in[7];
    const float* Wk    = (const float*)d_in[8];
    const float* bk    = (const float*)d_in[9];
    const float* Wv    = (const float*)d_in[10];
    const float* bv    = (const float*)d_in[11];
    const float* Wp    = (const float*)d_in[12];
    const float* Wo    = (const float*)d_in[13];
    const float* bo    = (const float*)d_in[14];
    float* out = (float*)d_out;

    const int BT = B_ * T_;       // 4096

    const size_t sz_bt = (size_t)BT * D_;            // 2,097,152
    const size_t sz_bl = (size_t)(B_ * L_) * D_;     // 4,192,256
    const size_t sz_w  = 512 * 512;
    const size_t need  = (5 * sz_bt + sz_bl + 5 * sz_w) * sizeof(bf16) + 1536 * sizeof(float);
    if (ws_size < need) return;

    // ws layout: y | o | q | k | v | p | Wqkv_t | Wp_t | Wo_t | biasq
    bf16* y       = (bf16*)d_ws;
    bf16* o       = y + sz_bt;
    bf16* q       = y + 2 * sz_bt;
    bf16* k       = y + 3 * sz_bt;
    bf16* v       = y + 4 * sz_bt;
    bf16* p       = y + 5 * sz_bt;
    bf16* Wqkv_t  = p + sz_bl;
    bf16* Wp_t    = Wqkv_t + 3 * sz_w;
    bf16* Wo_t    = Wp_t + sz_w;
    float* biasq  = (float*)(Wo_t + sz_w);
    // pos_bf scratch lives in d_out (8,388,608 B f32 region; pos_bf needs
    // 8188*512*2 = 8,384,512 B; p-GEMM OOB A-tile rows stay within the 8 MB).
    // gemm_out later overwrites every element of d_out.
    bf16* pos_bf  = (bf16*)d_out;

    prep_all<<<7429, 256, 0, stream>>>(Wq, Wk, Wv, Wp, Wo, bq, bk, bv, pos, x,
                                       gamma, beta, Wqkv_t, Wp_t, Wo_t, biasq, pos_bf, y);

    // qkv: 384 + p: 256 = 640 uniform 128x128 jobs, BK=32, single round
    gemm_qkvp<<<640, 256, 0, stream>>>(y, pos_bf, Wqkv_t, Wp_t, biasq, q, p, sz_bt);

    attn_mfma_kernel<<<dim3(T_ / 64, H_, B_), 256, 0, stream>>>(q, k, v, p, cb, pb, o);

    // out: [4096,512]x[512,512] + bo + x residual -> f32 d_out, 512 x 64x64 tiles
    gemm_out<<<512, 256, 0, stream>>>(o, Wo_t, bo, x, out);
}